// Round 3
// baseline (309.584 us; speedup 1.0000x reference)
//
#include <hip/hip_runtime.h>

// MHA: B=2, S=2048, D=1024, H=16, DK=DV=64
// out = softmax(mask(|QK^T/8|)) V, then output projection.
// All matmuls in bf16 MFMA (16x16x32), fp32 accumulate.

#define DI __device__ __forceinline__

typedef __bf16 bf16x8 __attribute__((ext_vector_type(8)));
typedef float f32x4 __attribute__((ext_vector_type(4)));
typedef unsigned short u16x8 __attribute__((ext_vector_type(8)));
typedef unsigned short u16x4 __attribute__((ext_vector_type(4)));

union U8 { u16x8 u; bf16x8 b; };
union PB { unsigned int w[4]; u16x8 u; bf16x8 b; };

DI unsigned short f2bf(float f) {            // round-to-nearest-even
  unsigned int u = __float_as_uint(f);
  u += 0x7FFFu + ((u >> 16) & 1u);
  return (unsigned short)(u >> 16);
}
DI unsigned int pack2(float a, float b) {
  return (unsigned int)f2bf(a) | ((unsigned int)f2bf(b) << 16);
}

// ---------------- kernel 0a: x fp32 -> bf16 ----------------
__global__ __launch_bounds__(256) void k_conv_x(const float* __restrict__ x,
                                                unsigned short* __restrict__ xb) {
  size_t i = ((size_t)blockIdx.x * 256 + threadIdx.x) * 4;
  float4 v = *(const float4*)(x + i);
  u16x4 o;
  o[0] = f2bf(v.x); o[1] = f2bf(v.y); o[2] = f2bf(v.z); o[3] = f2bf(v.w);
  *(u16x4*)(xb + i) = o;
}

// ---------------- kernel 0b: W[k][n] f32 -> Wt[n][k] bf16 (1024x1024) ----------------
__global__ __launch_bounds__(256) void k_transpose(
    const float* __restrict__ W0, const float* __restrict__ W1,
    const float* __restrict__ W2, const float* __restrict__ W3,
    unsigned short* __restrict__ T0, unsigned short* __restrict__ T1,
    unsigned short* __restrict__ T2, unsigned short* __restrict__ T3) {
  const int z = blockIdx.z;
  const float* W = (z == 0) ? W0 : (z == 1) ? W1 : (z == 2) ? W2 : W3;
  unsigned short* T = (z == 0) ? T0 : (z == 1) ? T1 : (z == 2) ? T2 : T3;
  __shared__ unsigned short buf[32][33];
  const int k0 = blockIdx.x * 32, n0 = blockIdx.y * 32;
  const int tx = threadIdx.x, ty = threadIdx.y;   // (32, 8)
#pragma unroll
  for (int j = 0; j < 4; ++j) {
    int r = ty + j * 8;
    buf[r][tx] = f2bf(W[(size_t)(k0 + r) * 1024 + n0 + tx]);
  }
  __syncthreads();
#pragma unroll
  for (int j = 0; j < 4; ++j) {
    int c = ty + j * 8;
    T[(size_t)(n0 + c) * 1024 + k0 + tx] = buf[tx][c];
  }
}

// ---------------- shared GEMM main loop ----------------
// C(128x128) = A(128xK) * Wt(128xK)^T, K=1024, bf16 MFMA 16x16x32.
// LDS stride 40 elems (80B = 5*16B): ds_read_b128-aligned, 2-way banks (free).
#define LDK 40

DI void gemm_main(const unsigned short* __restrict__ A,
                  const unsigned short* __restrict__ Bm,
                  unsigned short* As, unsigned short* Bs,
                  int m0, int n0, f32x4 acc[4][4]) {
  const int tid = threadIdx.x;
  const int lane = tid & 63, wid = tid >> 6;
  const int wr = wid >> 1, wc = wid & 1;
  const int g = lane >> 4, lq = lane & 15;
  const int srow = tid >> 2, sq = tid & 3;

  for (int k0 = 0; k0 < 1024; k0 += 32) {
    __syncthreads();
#pragma unroll
    for (int j = 0; j < 2; ++j) {
      int r = srow + j * 64;
      *(u16x8*)&As[r * LDK + sq * 8] =
          *(const u16x8*)&A[(size_t)(m0 + r) * 1024 + k0 + sq * 8];
      *(u16x8*)&Bs[r * LDK + sq * 8] =
          *(const u16x8*)&Bm[(size_t)(n0 + r) * 1024 + k0 + sq * 8];
    }
    __syncthreads();
    U8 af[4], bfr[4];
#pragma unroll
    for (int f = 0; f < 4; ++f) {
      af[f].u  = *(const u16x8*)&As[(wr * 64 + f * 16 + lq) * LDK + g * 8];
      bfr[f].u = *(const u16x8*)&Bs[(wc * 64 + f * 16 + lq) * LDK + g * 8];
    }
#pragma unroll
    for (int i = 0; i < 4; ++i)
#pragma unroll
      for (int j = 0; j < 4; ++j)
        acc[i][j] = __builtin_amdgcn_mfma_f32_16x16x32_bf16(af[i].b, bfr[j].b,
                                                            acc[i][j], 0, 0, 0);
  }
}

// ---------------- kernel 1: QKV projection ----------------
__global__ __launch_bounds__(256) void k_gemm_qkv(
    const unsigned short* __restrict__ xb,
    const unsigned short* __restrict__ Wqt, const unsigned short* __restrict__ Wkt,
    const unsigned short* __restrict__ Wvt,
    const float* __restrict__ bq, const float* __restrict__ bk,
    const float* __restrict__ bv,
    unsigned short* __restrict__ Qo, unsigned short* __restrict__ Ko,
    unsigned short* __restrict__ Vto) {
  __shared__ unsigned short As[128 * LDK];
  __shared__ unsigned short Bs[128 * LDK];
  const int z = blockIdx.z;
  const unsigned short* Bm = (z == 0) ? Wqt : (z == 1) ? Wkt : Wvt;
  const float* bias = (z == 0) ? bq : (z == 1) ? bk : bv;

  f32x4 acc[4][4];
#pragma unroll
  for (int i = 0; i < 4; ++i)
#pragma unroll
    for (int j = 0; j < 4; ++j) acc[i][j] = f32x4{0.f, 0.f, 0.f, 0.f};

  const int m0 = blockIdx.x * 128, n0 = blockIdx.y * 128;
  gemm_main(xb, Bm, As, Bs, m0, n0, acc);

  const int lane = threadIdx.x & 63, wid = threadIdx.x >> 6;
  const int wr = wid >> 1, wc = wid & 1;
  const int g = lane >> 4, lq = lane & 15;
  unsigned short* dstQK = (z == 0) ? Qo : Ko;
#pragma unroll
  for (int j = 0; j < 4; ++j) {
    int col = n0 + wc * 64 + j * 16 + lq;
    float bv_ = bias[col];
    int h = col >> 6, d = col & 63;
#pragma unroll
    for (int i = 0; i < 4; ++i) {
#pragma unroll
      for (int r = 0; r < 4; ++r) {
        int row = m0 + wr * 64 + i * 16 + g * 4 + r;
        int b = row >> 11, s = row & 2047;
        unsigned short hv = f2bf(acc[i][j][r] + bv_);
        if (z < 2)
          dstQK[(((size_t)(b * 16 + h)) * 2048 + s) * 64 + d] = hv;
        else
          Vto[(((size_t)(b * 16 + h)) * 64 + d) * 2048 + s] = hv;
      }
    }
  }
}

// ---------------- kernel 3: output projection (fp32 out + bias) ----------------
__global__ __launch_bounds__(256) void k_gemm_out(
    const unsigned short* __restrict__ Ob, const unsigned short* __restrict__ Wot,
    const float* __restrict__ bo, float* __restrict__ out) {
  __shared__ unsigned short As[128 * LDK];
  __shared__ unsigned short Bs[128 * LDK];
  f32x4 acc[4][4];
#pragma unroll
  for (int i = 0; i < 4; ++i)
#pragma unroll
    for (int j = 0; j < 4; ++j) acc[i][j] = f32x4{0.f, 0.f, 0.f, 0.f};

  const int m0 = blockIdx.x * 128, n0 = blockIdx.y * 128;
  gemm_main(Ob, Wot, As, Bs, m0, n0, acc);

  const int lane = threadIdx.x & 63, wid = threadIdx.x >> 6;
  const int wr = wid >> 1, wc = wid & 1;
  const int g = lane >> 4, lq = lane & 15;
#pragma unroll
  for (int j = 0; j < 4; ++j) {
    int col = n0 + wc * 64 + j * 16 + lq;
    float bv_ = bo[col];
#pragma unroll
    for (int i = 0; i < 4; ++i)
#pragma unroll
      for (int r = 0; r < 4; ++r) {
        int row = m0 + wr * 64 + i * 16 + g * 4 + r;
        out[(size_t)row * 1024 + col] = acc[i][j][r] + bv_;
      }
  }
}

// ---------------- kernel 2: flash attention, swapped-QK^T in-register softmax ----
// grid (32 qtiles [reversed: heavy first], 16 h, 2 b), block 256 (4 waves, 16 q each).
// Q,K: (B*H, 2048, 64) bf16; Vt: (B*H, 64, 2048) bf16; O: (B, 2048, 1024) bf16.
// St = mfma(A=K, B=Q): col=lane&15 = q, row = k. Softmax fully lane-local.
// P -> PV B-operand: dest lane (g,lq), word w, half hh needs source lane
// g' = (g&1)*2 + (w>>1), register c = hh*2 + (g>>1), pair p = w&1.
// Register index depends on DEST g -> shuffle both c candidates, select by g>>1.
__global__ __launch_bounds__(256) void k_flash(
    const unsigned short* __restrict__ Q, const unsigned short* __restrict__ Km,
    const unsigned short* __restrict__ Vt, unsigned short* __restrict__ O) {
  const int tid = threadIdx.x;
  const int lane = tid & 63, wid = tid >> 6;
  const int g = lane >> 4, lq = lane & 15;
  const int qt = gridDim.x - 1 - blockIdx.x;   // heavy blocks first
  const int h = blockIdx.y, b = blockIdx.z;
  const int bh = b * 16 + h;
  const int q0 = qt * 64;
  const size_t qkbase = (size_t)bh * 2048 * 64;
  const size_t vbase = (size_t)bh * 64 * 2048;
  const int qrow = q0 + wid * 16 + lq;         // this lane's q (MFMA col)

  // Q fragment (used as B operand): lane holds Q[qrow][g*8 + :8], two dk halves
  U8 aq0, aq1;
  {
    const unsigned short* qp = &Q[qkbase + (size_t)qrow * 64 + g * 8];
    aq0.u = *(const u16x8*)qp;
    aq1.u = *(const u16x8*)(qp + 32);
  }
  float m = -1e30f, l = 0.f;
  f32x4 oacc[4];   // O^T[dv = c*16 + g*4 + r][q = lq]
#pragma unroll
  for (int c = 0; c < 4; ++c) oacc[c] = f32x4{0.f, 0.f, 0.f, 0.f};

  const int nt = qt + 1;
  for (int t = 0; t < nt; ++t) {
    const int kk0 = t * 64;
    // ---- St = K Q^T (64 k x 16 q): A = K rows (k-contig), B = Q frag
    f32x4 sacc[4];
#pragma unroll
    for (int c = 0; c < 4; ++c) {
      const unsigned short* kp = &Km[qkbase + (size_t)(kk0 + c * 16 + lq) * 64 + g * 8];
      U8 b0, b1;
      b0.u = *(const u16x8*)kp;
      b1.u = *(const u16x8*)(kp + 32);
      sacc[c] = __builtin_amdgcn_mfma_f32_16x16x32_bf16(b0.b, aq0.b,
                                                        f32x4{0.f, 0.f, 0.f, 0.f}, 0, 0, 0);
      sacc[c] = __builtin_amdgcn_mfma_f32_16x16x32_bf16(b1.b, aq1.b, sacc[c], 0, 0, 0);
    }
    // ---- abs + causal + online softmax; lane owns q = qrow, k = kk0+c*16+g*4+r
    float val[4][4];
    float vmax = -1e30f;
#pragma unroll
    for (int c = 0; c < 4; ++c)
#pragma unroll
      for (int r = 0; r < 4; ++r) {
        int k = kk0 + c * 16 + g * 4 + r;
        float sv = fabsf(sacc[c][r] * 0.125f);
        sv = (k <= qrow) ? sv : -1e30f;
        val[c][r] = sv;
        vmax = fmaxf(vmax, sv);
      }
    vmax = fmaxf(vmax, __shfl_xor(vmax, 16, 64));
    vmax = fmaxf(vmax, __shfl_xor(vmax, 32, 64));
    float mn = fmaxf(m, vmax);
    float alpha = __expf(m - mn);
    m = mn;
    float s = 0.f;
#pragma unroll
    for (int c = 0; c < 4; ++c)
#pragma unroll
      for (int r = 0; r < 4; ++r) {
        float p = __expf(val[c][r] - mn);
        val[c][r] = p;
        s += p;
      }
    s += __shfl_xor(s, 16, 64);
    s += __shfl_xor(s, 32, 64);
    l = l * alpha + s;
#pragma unroll
    for (int c = 0; c < 4; ++c)
#pragma unroll
      for (int r = 0; r < 4; ++r) oacc[c][r] *= alpha;
    // ---- pack P^T (bf16 pairs, k-adjacent): pk[c][p] = P[k=c*16+g*4+2p,+1][q=lq]
    unsigned int pk[4][2];
#pragma unroll
    for (int c = 0; c < 4; ++c) {
      pk[c][0] = pack2(val[c][0], val[c][1]);
      pk[c][1] = pack2(val[c][2], val[c][3]);
    }
#pragma unroll
    for (int hh = 0; hh < 2; ++hh) {
      PB pb;
#pragma unroll
      for (int w = 0; w < 4; ++w) {
        int src = (((g & 1) * 2 + (w >> 1)) << 4) + lq;
        unsigned int lo = __shfl(pk[hh * 2 + 0][w & 1], src, 64);  // for dest g<2
        unsigned int hi = __shfl(pk[hh * 2 + 1][w & 1], src, 64);  // for dest g>=2
        pb.w[w] = (g >> 1) ? hi : lo;
      }
      // PV: A = V^T rows (dv = c*16+lq, s-contig), accumulate O^T
#pragma unroll
      for (int c = 0; c < 4; ++c) {
        const unsigned short* vp =
            &Vt[vbase + (size_t)(c * 16 + lq) * 2048 + kk0 + hh * 32 + g * 8];
        U8 va;
        va.u = *(const u16x8*)vp;
        oacc[c] = __builtin_amdgcn_mfma_f32_16x16x32_bf16(va.b, pb.b, oacc[c], 0, 0, 0);
      }
    }
  }
  // ---- epilogue: O[b][s=qrow][h*64+dv], dv = c*16 + g*4 + r (4 contiguous per c)
  float inv_l = 1.0f / l;
#pragma unroll
  for (int c = 0; c < 4; ++c) {
    u16x4 ov;
#pragma unroll
    for (int r = 0; r < 4; ++r) ov[r] = f2bf(oacc[c][r] * inv_l);
    *(u16x4*)&O[((size_t)(b * 2048 + qrow)) * 1024 + h * 64 + c * 16 + g * 4] = ov;
  }
}

// ---------------- launch ----------------
extern "C" void kernel_launch(void* const* d_in, const int* in_sizes, int n_in,
                              void* d_out, int out_size, void* d_ws, size_t ws_size,
                              hipStream_t stream) {
  const float* x  = (const float*)d_in[0];
  const float* Wq = (const float*)d_in[1];
  const float* bq = (const float*)d_in[2];
  const float* Wk = (const float*)d_in[3];
  const float* bk = (const float*)d_in[4];
  const float* Wv = (const float*)d_in[5];
  const float* bv = (const float*)d_in[6];
  const float* Wo = (const float*)d_in[7];
  const float* bo = (const float*)d_in[8];
  float* out = (float*)d_out;

  char* ws = (char*)d_ws;
  const size_t MB = 1024 * 1024;
  unsigned short* xb   = (unsigned short*)(ws + 0 * MB);   // 8 MB
  unsigned short* Wqt  = (unsigned short*)(ws + 8 * MB);   // 2 MB
  unsigned short* Wkt  = (unsigned short*)(ws + 10 * MB);  // 2 MB
  unsigned short* Wvt  = (unsigned short*)(ws + 12 * MB);  // 2 MB
  unsigned short* Wot  = (unsigned short*)(ws + 14 * MB);  // 2 MB
  unsigned short* Qws  = (unsigned short*)(ws + 16 * MB);  // 8 MB
  unsigned short* Kws  = (unsigned short*)(ws + 24 * MB);  // 8 MB
  unsigned short* Vtws = (unsigned short*)(ws + 32 * MB);  // 8 MB
  unsigned short* Ows  = (unsigned short*)(ws + 40 * MB);  // 8 MB

  k_conv_x<<<4096, 256, 0, stream>>>(x, xb);
  k_transpose<<<dim3(32, 32, 4), dim3(32, 8), 0, stream>>>(Wq, Wk, Wv, Wo,
                                                           Wqt, Wkt, Wvt, Wot);
  k_gemm_qkv<<<dim3(32, 8, 3), 256, 0, stream>>>(xb, Wqt, Wkt, Wvt, bq, bk, bv,
                                                 Qws, Kws, Vtws);
  k_flash<<<dim3(32, 16, 2), 256, 0, stream>>>(Qws, Kws, Vtws, Ows);
  k_gemm_out<<<dim3(32, 8), 256, 0, stream>>>(Ows, Wot, bo, out);
}

// Round 4
// 254.366 us; speedup vs baseline: 1.2171x; 1.2171x over previous
//
#include <hip/hip_runtime.h>

// MHA: B=2, S=2048, D=1024, H=16, DK=DV=64
// out = softmax(mask(|QK^T/8|)) V, then output projection.
// All matmuls in bf16 MFMA (16x16x32), fp32 accumulate.

#define DI __device__ __forceinline__

typedef __bf16 bf16x8 __attribute__((ext_vector_type(8)));
typedef float f32x4 __attribute__((ext_vector_type(4)));
typedef unsigned short u16x8 __attribute__((ext_vector_type(8)));
typedef unsigned short u16x4 __attribute__((ext_vector_type(4)));

union U8 { u16x8 u; bf16x8 b; };
union PB { unsigned int w[4]; u16x8 u; bf16x8 b; };

DI unsigned short f2bf(float f) {            // round-to-nearest-even
  unsigned int u = __float_as_uint(f);
  u += 0x7FFFu + ((u >> 16) & 1u);
  return (unsigned short)(u >> 16);
}
DI unsigned int pack2(float a, float b) {
  return (unsigned int)f2bf(a) | ((unsigned int)f2bf(b) << 16);
}

// ---------------- kernel 0a: x fp32 -> bf16 ----------------
__global__ __launch_bounds__(256) void k_conv_x(const float* __restrict__ x,
                                                unsigned short* __restrict__ xb) {
  size_t i = ((size_t)blockIdx.x * 256 + threadIdx.x) * 4;
  float4 v = *(const float4*)(x + i);
  u16x4 o;
  o[0] = f2bf(v.x); o[1] = f2bf(v.y); o[2] = f2bf(v.z); o[3] = f2bf(v.w);
  *(u16x4*)(xb + i) = o;
}

// ---------------- kernel 0b: W[k][n] f32 -> Wt[n][k] bf16 (1024x1024) ----------------
__global__ __launch_bounds__(256) void k_transpose(
    const float* __restrict__ W0, const float* __restrict__ W1,
    const float* __restrict__ W2, const float* __restrict__ W3,
    unsigned short* __restrict__ T0, unsigned short* __restrict__ T1,
    unsigned short* __restrict__ T2, unsigned short* __restrict__ T3) {
  const int z = blockIdx.z;
  const float* W = (z == 0) ? W0 : (z == 1) ? W1 : (z == 2) ? W2 : W3;
  unsigned short* T = (z == 0) ? T0 : (z == 1) ? T1 : (z == 2) ? T2 : T3;
  __shared__ unsigned short buf[32][33];
  const int k0 = blockIdx.x * 32, n0 = blockIdx.y * 32;
  const int tx = threadIdx.x, ty = threadIdx.y;   // (32, 8)
#pragma unroll
  for (int j = 0; j < 4; ++j) {
    int r = ty + j * 8;
    buf[r][tx] = f2bf(W[(size_t)(k0 + r) * 1024 + n0 + tx]);
  }
  __syncthreads();
#pragma unroll
  for (int j = 0; j < 4; ++j) {
    int c = ty + j * 8;
    T[(size_t)(n0 + c) * 1024 + k0 + tx] = buf[tx][c];
  }
}

// ---------------- shared GEMM main loop ----------------
// C(128x128) = A(128xK) * Wt(128xK)^T, K=1024, bf16 MFMA 16x16x32.
// LDS stride 40 elems (80B = 5*16B): ds_read_b128-aligned, 2-way banks (free).
#define LDK 40

DI void gemm_main(const unsigned short* __restrict__ A,
                  const unsigned short* __restrict__ Bm,
                  unsigned short* As, unsigned short* Bs,
                  int m0, int n0, f32x4 acc[4][4]) {
  const int tid = threadIdx.x;
  const int lane = tid & 63, wid = tid >> 6;
  const int wr = wid >> 1, wc = wid & 1;
  const int g = lane >> 4, lq = lane & 15;
  const int srow = tid >> 2, sq = tid & 3;

  for (int k0 = 0; k0 < 1024; k0 += 32) {
    __syncthreads();
#pragma unroll
    for (int j = 0; j < 2; ++j) {
      int r = srow + j * 64;
      *(u16x8*)&As[r * LDK + sq * 8] =
          *(const u16x8*)&A[(size_t)(m0 + r) * 1024 + k0 + sq * 8];
      *(u16x8*)&Bs[r * LDK + sq * 8] =
          *(const u16x8*)&Bm[(size_t)(n0 + r) * 1024 + k0 + sq * 8];
    }
    __syncthreads();
    U8 af[4], bfr[4];
#pragma unroll
    for (int f = 0; f < 4; ++f) {
      af[f].u  = *(const u16x8*)&As[(wr * 64 + f * 16 + lq) * LDK + g * 8];
      bfr[f].u = *(const u16x8*)&Bs[(wc * 64 + f * 16 + lq) * LDK + g * 8];
    }
#pragma unroll
    for (int i = 0; i < 4; ++i)
#pragma unroll
      for (int j = 0; j < 4; ++j)
        acc[i][j] = __builtin_amdgcn_mfma_f32_16x16x32_bf16(af[i].b, bfr[j].b,
                                                            acc[i][j], 0, 0, 0);
  }
}

// ---------------- kernel 1: QKV projection ----------------
__global__ __launch_bounds__(256) void k_gemm_qkv(
    const unsigned short* __restrict__ xb,
    const unsigned short* __restrict__ Wqt, const unsigned short* __restrict__ Wkt,
    const unsigned short* __restrict__ Wvt,
    const float* __restrict__ bq, const float* __restrict__ bk,
    const float* __restrict__ bv,
    unsigned short* __restrict__ Qo, unsigned short* __restrict__ Ko,
    unsigned short* __restrict__ Vto) {
  __shared__ unsigned short As[128 * LDK];
  __shared__ unsigned short Bs[128 * LDK];
  const int z = blockIdx.z;
  const unsigned short* Bm = (z == 0) ? Wqt : (z == 1) ? Wkt : Wvt;
  const float* bias = (z == 0) ? bq : (z == 1) ? bk : bv;

  f32x4 acc[4][4];
#pragma unroll
  for (int i = 0; i < 4; ++i)
#pragma unroll
    for (int j = 0; j < 4; ++j) acc[i][j] = f32x4{0.f, 0.f, 0.f, 0.f};

  const int m0 = blockIdx.x * 128, n0 = blockIdx.y * 128;
  gemm_main(xb, Bm, As, Bs, m0, n0, acc);

  const int lane = threadIdx.x & 63, wid = threadIdx.x >> 6;
  const int wr = wid >> 1, wc = wid & 1;
  const int g = lane >> 4, lq = lane & 15;
  unsigned short* dstQK = (z == 0) ? Qo : Ko;
#pragma unroll
  for (int j = 0; j < 4; ++j) {
    int col = n0 + wc * 64 + j * 16 + lq;
    float bv_ = bias[col];
    int h = col >> 6, d = col & 63;
#pragma unroll
    for (int i = 0; i < 4; ++i) {
#pragma unroll
      for (int r = 0; r < 4; ++r) {
        int row = m0 + wr * 64 + i * 16 + g * 4 + r;
        int b = row >> 11, s = row & 2047;
        unsigned short hv = f2bf(acc[i][j][r] + bv_);
        if (z < 2)
          dstQK[(((size_t)(b * 16 + h)) * 2048 + s) * 64 + d] = hv;
        else
          Vto[(((size_t)(b * 16 + h)) * 64 + d) * 2048 + s] = hv;
      }
    }
  }
}

// ---------------- kernel 3: output projection (fp32 out + bias) ----------------
__global__ __launch_bounds__(256) void k_gemm_out(
    const unsigned short* __restrict__ Ob, const unsigned short* __restrict__ Wot,
    const float* __restrict__ bo, float* __restrict__ out) {
  __shared__ unsigned short As[128 * LDK];
  __shared__ unsigned short Bs[128 * LDK];
  f32x4 acc[4][4];
#pragma unroll
  for (int i = 0; i < 4; ++i)
#pragma unroll
    for (int j = 0; j < 4; ++j) acc[i][j] = f32x4{0.f, 0.f, 0.f, 0.f};

  const int m0 = blockIdx.x * 128, n0 = blockIdx.y * 128;
  gemm_main(Ob, Wot, As, Bs, m0, n0, acc);

  const int lane = threadIdx.x & 63, wid = threadIdx.x >> 6;
  const int wr = wid >> 1, wc = wid & 1;
  const int g = lane >> 4, lq = lane & 15;
#pragma unroll
  for (int j = 0; j < 4; ++j) {
    int col = n0 + wc * 64 + j * 16 + lq;
    float bv_ = bo[col];
#pragma unroll
    for (int i = 0; i < 4; ++i)
#pragma unroll
      for (int r = 0; r < 4; ++r) {
        int row = m0 + wr * 64 + i * 16 + g * 4 + r;
        out[(size_t)row * 1024 + col] = acc[i][j][r] + bv_;
      }
  }
}

// ---------------- kernel 2: flash attention, swapped-QK^T, reg-prefetched K/V ----
// 1D grid 1024 blocks, XCD-swizzled: each XCD owns 4 (b,h) pairs (2MB K+V in its
// L2), q-tiles dispatched heavy-first. Block 256 (4 waves, 16 q each).
// K(t+1) loads issued right after QK(t) MFMAs consume kf (WAR overwrite in
// flight); V(t+1) after PV(t). No LDS/barriers -> compiler emits counted vmcnt,
// loads stay in flight across the iteration.
__global__ __launch_bounds__(256) void k_flash(
    const unsigned short* __restrict__ Q, const unsigned short* __restrict__ Km,
    const unsigned short* __restrict__ Vt, unsigned short* __restrict__ O) {
  const int tid = threadIdx.x;
  const int lane = tid & 63, wid = tid >> 6;
  const int g = lane >> 4, lq = lane & 15;
  const int bid = blockIdx.x;
  const int w = (bid & 7) * 128 + (bid >> 3);   // XCD-chunked, bijective (1024=8*128)
  const int qt = 31 - (w & 31);                 // heavy first within each XCD
  const int h = (w >> 5) & 15;
  const int b = w >> 9;
  const int bh = b * 16 + h;
  const int q0 = qt * 64;
  const size_t qkbase = (size_t)bh * 2048 * 64;
  const size_t vbase = (size_t)bh * 64 * 2048;
  const int qrow = q0 + wid * 16 + lq;          // this lane's q (MFMA col)

  // Q fragment (used as B operand): lane holds Q[qrow][g*8 + :8], two dk halves
  U8 aq0, aq1;
  {
    const unsigned short* qp = &Q[qkbase + (size_t)qrow * 64 + g * 8];
    aq0.u = *(const u16x8*)qp;
    aq1.u = *(const u16x8*)(qp + 32);
  }
  float m = -1e30f, l = 0.f;
  f32x4 oacc[4];   // O^T[dv = c*16 + g*4 + r][q = lq]
#pragma unroll
  for (int c = 0; c < 4; ++c) oacc[c] = f32x4{0.f, 0.f, 0.f, 0.f};

  const int nt = qt + 1;

  // ---- preload tile 0 into registers
  U8 kf[4][2], vf[4][2];
#pragma unroll
  for (int c = 0; c < 4; ++c) {
    const unsigned short* kp = &Km[qkbase + (size_t)(c * 16 + lq) * 64 + g * 8];
    kf[c][0].u = *(const u16x8*)kp;
    kf[c][1].u = *(const u16x8*)(kp + 32);
    const unsigned short* vp = &Vt[vbase + (size_t)(c * 16 + lq) * 2048 + g * 8];
    vf[c][0].u = *(const u16x8*)vp;
    vf[c][1].u = *(const u16x8*)(vp + 32);
  }

  for (int t = 0; t < nt; ++t) {
    const int kk0 = t * 64;
    // ---- St = K Q^T (64 k x 16 q): A = K rows, B = Q frag
    f32x4 sacc[4];
#pragma unroll
    for (int c = 0; c < 4; ++c) {
      sacc[c] = __builtin_amdgcn_mfma_f32_16x16x32_bf16(kf[c][0].b, aq0.b,
                                                        f32x4{0.f, 0.f, 0.f, 0.f}, 0, 0, 0);
      sacc[c] = __builtin_amdgcn_mfma_f32_16x16x32_bf16(kf[c][1].b, aq1.b, sacc[c], 0, 0, 0);
    }
    // ---- prefetch K(t+1): overwrites kf after the QK MFMAs have read it
    if (t + 1 < nt) {
      const int kn = kk0 + 64;
#pragma unroll
      for (int c = 0; c < 4; ++c) {
        const unsigned short* kp = &Km[qkbase + (size_t)(kn + c * 16 + lq) * 64 + g * 8];
        kf[c][0].u = *(const u16x8*)kp;
        kf[c][1].u = *(const u16x8*)(kp + 32);
      }
    }
    // ---- abs + causal + online softmax (in place on sacc); lane owns q = qrow
    float vmax = -1e30f;
#pragma unroll
    for (int c = 0; c < 4; ++c)
#pragma unroll
      for (int r = 0; r < 4; ++r) {
        int k = kk0 + c * 16 + g * 4 + r;
        float sv = fabsf(sacc[c][r] * 0.125f);
        sv = (k <= qrow) ? sv : -1e30f;
        sacc[c][r] = sv;
        vmax = fmaxf(vmax, sv);
      }
    vmax = fmaxf(vmax, __shfl_xor(vmax, 16, 64));
    vmax = fmaxf(vmax, __shfl_xor(vmax, 32, 64));
    float mn = fmaxf(m, vmax);
    float alpha = __expf(m - mn);
    m = mn;
    float s = 0.f;
#pragma unroll
    for (int c = 0; c < 4; ++c)
#pragma unroll
      for (int r = 0; r < 4; ++r) {
        float p = __expf(sacc[c][r] - mn);
        sacc[c][r] = p;
        s += p;
      }
    s += __shfl_xor(s, 16, 64);
    s += __shfl_xor(s, 32, 64);
    l = l * alpha + s;
#pragma unroll
    for (int c = 0; c < 4; ++c)
#pragma unroll
      for (int r = 0; r < 4; ++r) oacc[c][r] *= alpha;
    // ---- pack P^T (bf16 pairs, k-adjacent): pk[c][p] = P[k=c*16+g*4+2p,+1][q=lq]
    unsigned int pk[4][2];
#pragma unroll
    for (int c = 0; c < 4; ++c) {
      pk[c][0] = pack2(sacc[c][0], sacc[c][1]);
      pk[c][1] = pack2(sacc[c][2], sacc[c][3]);
    }
    // ---- re-fragment P to PV B-operand; PV: A = V^T rows, accumulate O^T
#pragma unroll
    for (int hh = 0; hh < 2; ++hh) {
      PB pb;
#pragma unroll
      for (int w2 = 0; w2 < 4; ++w2) {
        int src = (((g & 1) * 2 + (w2 >> 1)) << 4) + lq;
        unsigned int lo = __shfl(pk[hh * 2 + 0][w2 & 1], src, 64);  // dest g<2
        unsigned int hi = __shfl(pk[hh * 2 + 1][w2 & 1], src, 64);  // dest g>=2
        pb.w[w2] = (g >> 1) ? hi : lo;
      }
#pragma unroll
      for (int c = 0; c < 4; ++c)
        oacc[c] = __builtin_amdgcn_mfma_f32_16x16x32_bf16(vf[c][hh].b, pb.b, oacc[c], 0, 0, 0);
    }
    // ---- prefetch V(t+1): overwrites vf after the PV MFMAs have read it
    if (t + 1 < nt) {
      const int kn = kk0 + 64;
#pragma unroll
      for (int c = 0; c < 4; ++c) {
        const unsigned short* vp = &Vt[vbase + (size_t)(c * 16 + lq) * 2048 + kn + g * 8];
        vf[c][0].u = *(const u16x8*)vp;
        vf[c][1].u = *(const u16x8*)(vp + 32);
      }
    }
  }
  // ---- epilogue: O[b][s=qrow][h*64+dv], dv = c*16 + g*4 + r (4 contiguous per c)
  float inv_l = 1.0f / l;
#pragma unroll
  for (int c = 0; c < 4; ++c) {
    u16x4 ov;
#pragma unroll
    for (int r = 0; r < 4; ++r) ov[r] = f2bf(oacc[c][r] * inv_l);
    *(u16x4*)&O[((size_t)(b * 2048 + qrow)) * 1024 + h * 64 + c * 16 + g * 4] = ov;
  }
}

// ---------------- launch ----------------
extern "C" void kernel_launch(void* const* d_in, const int* in_sizes, int n_in,
                              void* d_out, int out_size, void* d_ws, size_t ws_size,
                              hipStream_t stream) {
  const float* x  = (const float*)d_in[0];
  const float* Wq = (const float*)d_in[1];
  const float* bq = (const float*)d_in[2];
  const float* Wk = (const float*)d_in[3];
  const float* bk = (const float*)d_in[4];
  const float* Wv = (const float*)d_in[5];
  const float* bv = (const float*)d_in[6];
  const float* Wo = (const float*)d_in[7];
  const float* bo = (const float*)d_in[8];
  float* out = (float*)d_out;

  char* ws = (char*)d_ws;
  const size_t MB = 1024 * 1024;
  unsigned short* xb   = (unsigned short*)(ws + 0 * MB);   // 8 MB
  unsigned short* Wqt  = (unsigned short*)(ws + 8 * MB);   // 2 MB
  unsigned short* Wkt  = (unsigned short*)(ws + 10 * MB);  // 2 MB
  unsigned short* Wvt  = (unsigned short*)(ws + 12 * MB);  // 2 MB
  unsigned short* Wot  = (unsigned short*)(ws + 14 * MB);  // 2 MB
  unsigned short* Qws  = (unsigned short*)(ws + 16 * MB);  // 8 MB
  unsigned short* Kws  = (unsigned short*)(ws + 24 * MB);  // 8 MB
  unsigned short* Vtws = (unsigned short*)(ws + 32 * MB);  // 8 MB
  unsigned short* Ows  = (unsigned short*)(ws + 40 * MB);  // 8 MB

  k_conv_x<<<4096, 256, 0, stream>>>(x, xb);
  k_transpose<<<dim3(32, 32, 4), dim3(32, 8), 0, stream>>>(Wq, Wk, Wv, Wo,
                                                           Wqt, Wkt, Wvt, Wot);
  k_gemm_qkv<<<dim3(32, 8, 3), 256, 0, stream>>>(xb, Wqt, Wkt, Wvt, bq, bk, bv,
                                                 Qws, Kws, Vtws);
  k_flash<<<1024, 256, 0, stream>>>(Qws, Kws, Vtws, Ows);
  k_gemm_out<<<dim3(32, 8), 256, 0, stream>>>(Ows, Wot, bo, out);
}

// Round 5
// 174.487 us; speedup vs baseline: 1.7743x; 1.4578x over previous
//
#include <hip/hip_runtime.h>

// MHA: B=2, S=2048, D=1024, H=16, DK=DV=64
// out = softmax(mask(|QK^T/8|)) V, then output projection.
// All matmuls in bf16 MFMA (16x16x32), fp32 accumulate.
// Round 4: LDS-staged K/V + GEMM tiles via global_load_lds(16B), double-buffered,
// chunk-XOR swizzle on the global source (gload_lds writes linearly).

#define DI __device__ __forceinline__

typedef __bf16 bf16x8 __attribute__((ext_vector_type(8)));
typedef float f32x4 __attribute__((ext_vector_type(4)));
typedef unsigned short u16x8 __attribute__((ext_vector_type(8)));
typedef unsigned short u16x4 __attribute__((ext_vector_type(4)));

union U8 { u16x8 u; bf16x8 b; };
union PB { unsigned int w[4]; u16x8 u; bf16x8 b; };

typedef const __attribute__((address_space(1))) unsigned int* gas_p;
typedef __attribute__((address_space(3))) unsigned int* las_p;

DI void gload16(const unsigned short* g, unsigned short* l) {
  __builtin_amdgcn_global_load_lds((gas_p)(const void*)g, (las_p)(void*)l, 16, 0, 0);
}

DI unsigned short f2bf(float f) {            // round-to-nearest-even
  unsigned int u = __float_as_uint(f);
  u += 0x7FFFu + ((u >> 16) & 1u);
  return (unsigned short)(u >> 16);
}
DI unsigned int pack2(float a, float b) {
  return (unsigned int)f2bf(a) | ((unsigned int)f2bf(b) << 16);
}

// ---------------- kernel 0a: x fp32 -> bf16 ----------------
__global__ __launch_bounds__(256) void k_conv_x(const float* __restrict__ x,
                                                unsigned short* __restrict__ xb) {
  size_t i = ((size_t)blockIdx.x * 256 + threadIdx.x) * 4;
  float4 v = *(const float4*)(x + i);
  u16x4 o;
  o[0] = f2bf(v.x); o[1] = f2bf(v.y); o[2] = f2bf(v.z); o[3] = f2bf(v.w);
  *(u16x4*)(xb + i) = o;
}

// ---------------- kernel 0b: W[k][n] f32 -> Wt[n][k] bf16 (1024x1024) ----------------
__global__ __launch_bounds__(256) void k_transpose(
    const float* __restrict__ W0, const float* __restrict__ W1,
    const float* __restrict__ W2, const float* __restrict__ W3,
    unsigned short* __restrict__ T0, unsigned short* __restrict__ T1,
    unsigned short* __restrict__ T2, unsigned short* __restrict__ T3) {
  const int z = blockIdx.z;
  const float* W = (z == 0) ? W0 : (z == 1) ? W1 : (z == 2) ? W2 : W3;
  unsigned short* T = (z == 0) ? T0 : (z == 1) ? T1 : (z == 2) ? T2 : T3;
  __shared__ unsigned short buf[32][33];
  const int k0 = blockIdx.x * 32, n0 = blockIdx.y * 32;
  const int tx = threadIdx.x, ty = threadIdx.y;   // (32, 8)
#pragma unroll
  for (int j = 0; j < 4; ++j) {
    int r = ty + j * 8;
    buf[r][tx] = f2bf(W[(size_t)(k0 + r) * 1024 + n0 + tx]);
  }
  __syncthreads();
#pragma unroll
  for (int j = 0; j < 4; ++j) {
    int c = ty + j * 8;
    T[(size_t)(n0 + c) * 1024 + k0 + tx] = buf[tx][c];
  }
}

// ---------------- shared GEMM main loop (v2: gload_lds + dbuf) ----------------
// C(128x128) = A(128xK) * Wt(128xK)^T, K=1024, bf16 MFMA 16x16x32, BK=32.
// LDS tile [128][32] linear (64B rows, 4x16B chunks); source pre-swizzled with
// chunk ^= row&3 so frag ds_read_b128 spreads uniformly over banks.
DI void stage_gemm(const unsigned short* __restrict__ src, unsigned short* dst,
                   int row0, int k0, int tid, int wid) {
#pragma unroll
  for (int i = 0; i < 2; ++i) {
    int T = i * 256 + tid;
    int row = T >> 2, ch = T & 3;
    int sch = ch ^ (row & 3);
    gload16(&src[(size_t)(row0 + row) * 1024 + k0 + sch * 8],
            &dst[(i * 256 + wid * 64) * 8]);
  }
}

DI void gemm_main(const unsigned short* __restrict__ A,
                  const unsigned short* __restrict__ Bm,
                  unsigned short* As, unsigned short* Bs,
                  int m0, int n0, f32x4 acc[4][4]) {
  const int tid = threadIdx.x;
  const int lane = tid & 63, wid = tid >> 6;
  const int wr = wid >> 1, wc = wid & 1;
  const int g = lane >> 4, lq = lane & 15;

  stage_gemm(A, As, m0, 0, tid, wid);
  stage_gemm(Bm, Bs, n0, 0, tid, wid);
  __syncthreads();
  int buf = 0;
  for (int k0 = 0; k0 < 1024; k0 += 32) {
    if (k0 + 32 < 1024) {
      stage_gemm(A, As + (buf ^ 1) * 4096, m0, k0 + 32, tid, wid);
      stage_gemm(Bm, Bs + (buf ^ 1) * 4096, n0, k0 + 32, tid, wid);
    }
    const unsigned short* Ab = As + buf * 4096;
    const unsigned short* Bb = Bs + buf * 4096;
    U8 af[4], bfr[4];
#pragma unroll
    for (int f = 0; f < 4; ++f) {
      af[f].u  = *(const u16x8*)&Ab[(wr * 64 + f * 16 + lq) * 32 + ((g ^ (lq & 3)) * 8)];
      bfr[f].u = *(const u16x8*)&Bb[(wc * 64 + f * 16 + lq) * 32 + ((g ^ (lq & 3)) * 8)];
    }
#pragma unroll
    for (int i = 0; i < 4; ++i)
#pragma unroll
      for (int j = 0; j < 4; ++j)
        acc[i][j] = __builtin_amdgcn_mfma_f32_16x16x32_bf16(af[i].b, bfr[j].b,
                                                            acc[i][j], 0, 0, 0);
    __syncthreads();
    buf ^= 1;
  }
}

// ---------------- kernel 1: QKV projection ----------------
__global__ __launch_bounds__(256) void k_gemm_qkv(
    const unsigned short* __restrict__ xb,
    const unsigned short* __restrict__ Wqt, const unsigned short* __restrict__ Wkt,
    const unsigned short* __restrict__ Wvt,
    const float* __restrict__ bq, const float* __restrict__ bk,
    const float* __restrict__ bv,
    unsigned short* __restrict__ Qo, unsigned short* __restrict__ Ko,
    unsigned short* __restrict__ Vto) {
  __shared__ unsigned short As[2 * 4096];
  __shared__ unsigned short Bs[2 * 4096];
  const int z = blockIdx.z;
  const unsigned short* Bm = (z == 0) ? Wqt : (z == 1) ? Wkt : Wvt;
  const float* bias = (z == 0) ? bq : (z == 1) ? bk : bv;

  f32x4 acc[4][4];
#pragma unroll
  for (int i = 0; i < 4; ++i)
#pragma unroll
    for (int j = 0; j < 4; ++j) acc[i][j] = f32x4{0.f, 0.f, 0.f, 0.f};

  const int m0 = blockIdx.x * 128, n0 = blockIdx.y * 128;
  gemm_main(xb, Bm, As, Bs, m0, n0, acc);

  const int lane = threadIdx.x & 63, wid = threadIdx.x >> 6;
  const int wr = wid >> 1, wc = wid & 1;
  const int g = lane >> 4, lq = lane & 15;
  unsigned short* dstQK = (z == 0) ? Qo : Ko;
#pragma unroll
  for (int j = 0; j < 4; ++j) {
    int col = n0 + wc * 64 + j * 16 + lq;
    float bv_ = bias[col];
    int h = col >> 6, d = col & 63;
#pragma unroll
    for (int i = 0; i < 4; ++i) {
#pragma unroll
      for (int r = 0; r < 4; ++r) {
        int row = m0 + wr * 64 + i * 16 + g * 4 + r;
        int b = row >> 11, s = row & 2047;
        unsigned short hv = f2bf(acc[i][j][r] + bv_);
        if (z < 2)
          dstQK[(((size_t)(b * 16 + h)) * 2048 + s) * 64 + d] = hv;
        else
          Vto[(((size_t)(b * 16 + h)) * 64 + d) * 2048 + s] = hv;
      }
    }
  }
}

// ---------------- kernel 3: output projection (fp32 out + bias) ----------------
__global__ __launch_bounds__(256) void k_gemm_out(
    const unsigned short* __restrict__ Ob, const unsigned short* __restrict__ Wot,
    const float* __restrict__ bo, float* __restrict__ out) {
  __shared__ unsigned short As[2 * 4096];
  __shared__ unsigned short Bs[2 * 4096];
  f32x4 acc[4][4];
#pragma unroll
  for (int i = 0; i < 4; ++i)
#pragma unroll
    for (int j = 0; j < 4; ++j) acc[i][j] = f32x4{0.f, 0.f, 0.f, 0.f};

  const int m0 = blockIdx.x * 128, n0 = blockIdx.y * 128;
  gemm_main(Ob, Wot, As, Bs, m0, n0, acc);

  const int lane = threadIdx.x & 63, wid = threadIdx.x >> 6;
  const int wr = wid >> 1, wc = wid & 1;
  const int g = lane >> 4, lq = lane & 15;
#pragma unroll
  for (int j = 0; j < 4; ++j) {
    int col = n0 + wc * 64 + j * 16 + lq;
    float bv_ = bo[col];
#pragma unroll
    for (int i = 0; i < 4; ++i)
#pragma unroll
      for (int r = 0; r < 4; ++r) {
        int row = m0 + wr * 64 + i * 16 + g * 4 + r;
        out[(size_t)row * 1024 + col] = acc[i][j][r] + bv_;
      }
  }
}

// ---------------- kernel 2: flash attention v4 ------------------------------
// Block 256 thr (4 waves), each wave owns 32 q rows (two 16-q groups A/B);
// block = 128 q rows. Grid 512 = 8 XCD chunks x 64; each XCD owns 4 bh
// (K+V = 2MB, fits its L2); heavy q-blocks first.
// K/V 64-k tiles staged in LDS (double-buffered, global_load_lds 16B,
// source chunk-XOR pre-swizzle ch^=row&7), shared by all 4 waves.
// Swapped QK^T: St = mfma(A=Kfrag, B=Qfrag), lane owns q = col. Softmax
// in-register; P re-fragmented to PV B-operand by computed shuffles;
// PV: O^T = mfma(A=V^T frag, B=P^T).
DI void softmax_step(f32x4 sacc[4], float& m, float& l, f32x4 oacc[4],
                     unsigned int pk[4][2], int kk0, int qrow, int g) {
  float vmax = -1e30f;
#pragma unroll
  for (int c = 0; c < 4; ++c)
#pragma unroll
    for (int r = 0; r < 4; ++r) {
      int k = kk0 + c * 16 + g * 4 + r;
      float sv = fabsf(sacc[c][r] * 0.125f);
      sv = (k <= qrow) ? sv : -1e30f;
      sacc[c][r] = sv;
      vmax = fmaxf(vmax, sv);
    }
  vmax = fmaxf(vmax, __shfl_xor(vmax, 16, 64));
  vmax = fmaxf(vmax, __shfl_xor(vmax, 32, 64));
  float mn = fmaxf(m, vmax);
  float alpha = __expf(m - mn);
  m = mn;
  float s = 0.f;
#pragma unroll
  for (int c = 0; c < 4; ++c)
#pragma unroll
    for (int r = 0; r < 4; ++r) {
      float p = __expf(sacc[c][r] - mn);
      sacc[c][r] = p;
      s += p;
    }
  s += __shfl_xor(s, 16, 64);
  s += __shfl_xor(s, 32, 64);
  l = l * alpha + s;
#pragma unroll
  for (int c = 0; c < 4; ++c)
#pragma unroll
    for (int r = 0; r < 4; ++r) oacc[c][r] *= alpha;
#pragma unroll
  for (int c = 0; c < 4; ++c) {
    pk[c][0] = pack2(sacc[c][0], sacc[c][1]);
    pk[c][1] = pack2(sacc[c][2], sacc[c][3]);
  }
}

__global__ __launch_bounds__(256) void k_flash(
    const unsigned short* __restrict__ Q, const unsigned short* __restrict__ Km,
    const unsigned short* __restrict__ Vt, unsigned short* __restrict__ O) {
  const int tid = threadIdx.x;
  const int lane = tid & 63, wid = tid >> 6;
  const int g = lane >> 4, lq = lane & 15;
  const int bid = blockIdx.x;
  const int w = (bid & 7) * 64 + (bid >> 3);    // XCD-chunked, bijective (512=8*64)
  const int qb = 15 - (w & 15);                 // heavy first within each XCD
  const int bh = w >> 4;                        // 4 bh per XCD
  const int b = bh >> 4, h = bh & 15;
  const int q0 = qb * 128;
  const size_t qkbase = (size_t)bh * 2048 * 64;
  const size_t vbase = (size_t)bh * 64 * 2048;
  const int qrowA = q0 + wid * 32 + lq;         // this lane's q for group A
  const int qrowB = qrowA + 16;                 // and group B

  __shared__ unsigned short Ks[2][64 * 64];
  __shared__ unsigned short Vs[2][64 * 64];

  // Q fragments (B operand): lane holds Q[qrow][g*8 + :8], two dk halves
  U8 aq0A, aq1A, aq0B, aq1B;
  {
    const unsigned short* qp = &Q[qkbase + (size_t)qrowA * 64 + g * 8];
    aq0A.u = *(const u16x8*)qp;
    aq1A.u = *(const u16x8*)(qp + 32);
    const unsigned short* qp2 = &Q[qkbase + (size_t)qrowB * 64 + g * 8];
    aq0B.u = *(const u16x8*)qp2;
    aq1B.u = *(const u16x8*)(qp2 + 32);
  }
  float mA = -1e30f, lA = 0.f, mB = -1e30f, lB = 0.f;
  f32x4 oaccA[4], oaccB[4];   // O^T[dv = c*16 + g*4 + r][q = lq]
#pragma unroll
  for (int c = 0; c < 4; ++c) {
    oaccA[c] = f32x4{0.f, 0.f, 0.f, 0.f};
    oaccB[c] = f32x4{0.f, 0.f, 0.f, 0.f};
  }

  const int nt = 2 * qb + 2;

  // stage(buf, t): K tile rows=k (64x64), V tile rows=dv (64x64), 16B/thread x2
  auto stage = [&](int buf, int t) {
    const int kk0 = t * 64;
#pragma unroll
    for (int i = 0; i < 2; ++i) {
      int T = i * 256 + tid;
      int row = T >> 3, ch = T & 7;
      int sch = ch ^ (row & 7);
      gload16(&Km[qkbase + (size_t)(kk0 + row) * 64 + sch * 8],
              &Ks[buf][(i * 2048 + wid * 512)]);
      gload16(&Vt[vbase + (size_t)row * 2048 + kk0 + sch * 8],
              &Vs[buf][(i * 2048 + wid * 512)]);
    }
  };

  stage(0, 0);
  __syncthreads();
  int buf = 0;
  for (int t = 0; t < nt; ++t) {
    const int kk0 = t * 64;
    if (t + 1 < nt) stage(buf ^ 1, t + 1);

    // ---- QK^T: A = K frags from LDS, B = Q frags (groups A,B share K reads)
    f32x4 saccA[4], saccB[4];
#pragma unroll
    for (int c = 0; c < 4; ++c) {
      U8 kf0, kf1;
      kf0.u = *(const u16x8*)&Ks[buf][(c * 16 + lq) * 64 + (((0 * 4 + g) ^ (lq & 7)) * 8)];
      kf1.u = *(const u16x8*)&Ks[buf][(c * 16 + lq) * 64 + (((1 * 4 + g) ^ (lq & 7)) * 8)];
      saccA[c] = __builtin_amdgcn_mfma_f32_16x16x32_bf16(kf0.b, aq0A.b,
                                                         f32x4{0.f, 0.f, 0.f, 0.f}, 0, 0, 0);
      saccA[c] = __builtin_amdgcn_mfma_f32_16x16x32_bf16(kf1.b, aq1A.b, saccA[c], 0, 0, 0);
      saccB[c] = __builtin_amdgcn_mfma_f32_16x16x32_bf16(kf0.b, aq0B.b,
                                                         f32x4{0.f, 0.f, 0.f, 0.f}, 0, 0, 0);
      saccB[c] = __builtin_amdgcn_mfma_f32_16x16x32_bf16(kf1.b, aq1B.b, saccB[c], 0, 0, 0);
    }
    // ---- softmax (two independent chains)
    unsigned int pkA[4][2], pkB[4][2];
    softmax_step(saccA, mA, lA, oaccA, pkA, kk0, qrowA, g);
    softmax_step(saccB, mB, lB, oaccB, pkB, kk0, qrowB, g);
    // ---- re-fragment P; PV: A = V^T frags from LDS (shared by A,B)
#pragma unroll
    for (int hh = 0; hh < 2; ++hh) {
      PB pbA, pbB;
#pragma unroll
      for (int w2 = 0; w2 < 4; ++w2) {
        int src = (((g & 1) * 2 + (w2 >> 1)) << 4) + lq;
        unsigned int loA = __shfl(pkA[hh * 2 + 0][w2 & 1], src, 64);
        unsigned int hiA = __shfl(pkA[hh * 2 + 1][w2 & 1], src, 64);
        pbA.w[w2] = (g >> 1) ? hiA : loA;
        unsigned int loB = __shfl(pkB[hh * 2 + 0][w2 & 1], src, 64);
        unsigned int hiB = __shfl(pkB[hh * 2 + 1][w2 & 1], src, 64);
        pbB.w[w2] = (g >> 1) ? hiB : loB;
      }
#pragma unroll
      for (int c = 0; c < 4; ++c) {
        U8 vf;
        vf.u = *(const u16x8*)&Vs[buf][(c * 16 + lq) * 64 + (((hh * 4 + g) ^ (lq & 7)) * 8)];
        oaccA[c] = __builtin_amdgcn_mfma_f32_16x16x32_bf16(vf.b, pbA.b, oaccA[c], 0, 0, 0);
        oaccB[c] = __builtin_amdgcn_mfma_f32_16x16x32_bf16(vf.b, pbB.b, oaccB[c], 0, 0, 0);
      }
    }
    __syncthreads();
    buf ^= 1;
  }
  // ---- epilogue: O[b][s=qrow][h*64+dv], dv = c*16 + g*4 + r
  float invA = 1.0f / lA, invB = 1.0f / lB;
#pragma unroll
  for (int c = 0; c < 4; ++c) {
    u16x4 ovA, ovB;
#pragma unroll
    for (int r = 0; r < 4; ++r) {
      ovA[r] = f2bf(oaccA[c][r] * invA);
      ovB[r] = f2bf(oaccB[c][r] * invB);
    }
    *(u16x4*)&O[((size_t)(b * 2048 + qrowA)) * 1024 + h * 64 + c * 16 + g * 4] = ovA;
    *(u16x4*)&O[((size_t)(b * 2048 + qrowB)) * 1024 + h * 64 + c * 16 + g * 4] = ovB;
  }
}

// ---------------- launch ----------------
extern "C" void kernel_launch(void* const* d_in, const int* in_sizes, int n_in,
                              void* d_out, int out_size, void* d_ws, size_t ws_size,
                              hipStream_t stream) {
  const float* x  = (const float*)d_in[0];
  const float* Wq = (const float*)d_in[1];
  const float* bq = (const float*)d_in[2];
  const float* Wk = (const float*)d_in[3];
  const float* bk = (const float*)d_in[4];
  const float* Wv = (const float*)d_in[5];
  const float* bv = (const float*)d_in[6];
  const float* Wo = (const float*)d_in[7];
  const float* bo = (const float*)d_in[8];
  float* out = (float*)d_out;

  char* ws = (char*)d_ws;
  const size_t MB = 1024 * 1024;
  unsigned short* xb   = (unsigned short*)(ws + 0 * MB);   // 8 MB
  unsigned short* Wqt  = (unsigned short*)(ws + 8 * MB);   // 2 MB
  unsigned short* Wkt  = (unsigned short*)(ws + 10 * MB);  // 2 MB
  unsigned short* Wvt  = (unsigned short*)(ws + 12 * MB);  // 2 MB
  unsigned short* Wot  = (unsigned short*)(ws + 14 * MB);  // 2 MB
  unsigned short* Qws  = (unsigned short*)(ws + 16 * MB);  // 8 MB
  unsigned short* Kws  = (unsigned short*)(ws + 24 * MB);  // 8 MB
  unsigned short* Vtws = (unsigned short*)(ws + 32 * MB);  // 8 MB
  unsigned short* Ows  = (unsigned short*)(ws + 40 * MB);  // 8 MB

  k_conv_x<<<4096, 256, 0, stream>>>(x, xb);
  k_transpose<<<dim3(32, 32, 4), dim3(32, 8), 0, stream>>>(Wq, Wk, Wv, Wo,
                                                           Wqt, Wkt, Wvt, Wot);
  k_gemm_qkv<<<dim3(32, 8, 3), 256, 0, stream>>>(xb, Wqt, Wkt, Wvt, bq, bk, bv,
                                                 Qws, Kws, Vtws);
  k_flash<<<512, 256, 0, stream>>>(Qws, Kws, Vtws, Ows);
  k_gemm_out<<<dim3(32, 8), 256, 0, stream>>>(Ows, Wot, bo, out);
}

// Round 6
// 162.549 us; speedup vs baseline: 1.9046x; 1.0734x over previous
//
#include <hip/hip_runtime.h>

// MHA: B=2, S=2048, D=1024, H=16, DK=DV=64
// out = softmax(mask(|QK^T/8|)) V, then output projection.
// All matmuls in bf16 MFMA (16x16x32), fp32 accumulate.
// Round 6: counted-vmcnt double-buffer pipeline (raw s_barrier + s_waitcnt
// vmcnt(4), never drain-to-0 mid-loop) in flash AND GEMMs; flash blocks pair
// q-blocks (qb, 15-qb) for perfectly uniform work (34 k-tiles/block).

#define DI __device__ __forceinline__

typedef __bf16 bf16x8 __attribute__((ext_vector_type(8)));
typedef float f32x4 __attribute__((ext_vector_type(4)));
typedef unsigned short u16x8 __attribute__((ext_vector_type(8)));
typedef unsigned short u16x4 __attribute__((ext_vector_type(4)));

union U8 { u16x8 u; bf16x8 b; };
union PB { unsigned int w[4]; u16x8 u; bf16x8 b; };

typedef const __attribute__((address_space(1))) unsigned int* gas_p;
typedef __attribute__((address_space(3))) unsigned int* las_p;

DI void gload16(const unsigned short* g, unsigned short* l) {
  __builtin_amdgcn_global_load_lds((gas_p)(const void*)g, (las_p)(void*)l, 16, 0, 0);
}

#define WAIT_VM4  asm volatile("s_waitcnt vmcnt(4)" ::: "memory")
#define WAIT_VM0  asm volatile("s_waitcnt vmcnt(0)" ::: "memory")
#define WAIT_LGKM asm volatile("s_waitcnt lgkmcnt(0)" ::: "memory")
#define BARRIER   __builtin_amdgcn_s_barrier()

DI unsigned short f2bf(float f) {            // round-to-nearest-even
  unsigned int u = __float_as_uint(f);
  u += 0x7FFFu + ((u >> 16) & 1u);
  return (unsigned short)(u >> 16);
}
DI unsigned int pack2(float a, float b) {
  return (unsigned int)f2bf(a) | ((unsigned int)f2bf(b) << 16);
}

// ---------------- kernel 0a: x fp32 -> bf16 ----------------
__global__ __launch_bounds__(256) void k_conv_x(const float* __restrict__ x,
                                                unsigned short* __restrict__ xb) {
  size_t i = ((size_t)blockIdx.x * 256 + threadIdx.x) * 4;
  float4 v = *(const float4*)(x + i);
  u16x4 o;
  o[0] = f2bf(v.x); o[1] = f2bf(v.y); o[2] = f2bf(v.z); o[3] = f2bf(v.w);
  *(u16x4*)(xb + i) = o;
}

// ---------------- kernel 0b: W[k][n] f32 -> Wt[n][k] bf16 (1024x1024) ----------------
__global__ __launch_bounds__(256) void k_transpose(
    const float* __restrict__ W0, const float* __restrict__ W1,
    const float* __restrict__ W2, const float* __restrict__ W3,
    unsigned short* __restrict__ T0, unsigned short* __restrict__ T1,
    unsigned short* __restrict__ T2, unsigned short* __restrict__ T3) {
  const int z = blockIdx.z;
  const float* W = (z == 0) ? W0 : (z == 1) ? W1 : (z == 2) ? W2 : W3;
  unsigned short* T = (z == 0) ? T0 : (z == 1) ? T1 : (z == 2) ? T2 : T3;
  __shared__ unsigned short buf[32][33];
  const int k0 = blockIdx.x * 32, n0 = blockIdx.y * 32;
  const int tx = threadIdx.x, ty = threadIdx.y;   // (32, 8)
#pragma unroll
  for (int j = 0; j < 4; ++j) {
    int r = ty + j * 8;
    buf[r][tx] = f2bf(W[(size_t)(k0 + r) * 1024 + n0 + tx]);
  }
  __syncthreads();
#pragma unroll
  for (int j = 0; j < 4; ++j) {
    int c = ty + j * 8;
    T[(size_t)(n0 + c) * 1024 + k0 + tx] = buf[tx][c];
  }
}

// ---------------- shared GEMM main loop (counted-vmcnt dbuf) ----------------
// C(128x128) = A(128xK) * Wt(128xK)^T, K=1024, bf16 MFMA 16x16x32, BK=32.
// LDS tile [128][32] linear; source pre-swizzled chunk ^= row&3.
// Each stage_gemm = 2 gload16/thread; A+B = 4/tile -> vmcnt(4) = 1 tile in flight.
DI void stage_gemm(const unsigned short* __restrict__ src, unsigned short* dst,
                   int row0, int k0, int tid, int wid) {
#pragma unroll
  for (int i = 0; i < 2; ++i) {
    int T = i * 256 + tid;
    int row = T >> 2, ch = T & 3;
    int sch = ch ^ (row & 3);
    gload16(&src[(size_t)(row0 + row) * 1024 + k0 + sch * 8],
            &dst[(i * 256 + wid * 64) * 8]);
  }
}

DI void gemm_main(const unsigned short* __restrict__ A,
                  const unsigned short* __restrict__ Bm,
                  unsigned short* As, unsigned short* Bs,
                  int m0, int n0, f32x4 acc[4][4]) {
  const int tid = threadIdx.x;
  const int lane = tid & 63, wid = tid >> 6;
  const int wr = wid >> 1, wc = wid & 1;
  const int g = lane >> 4, lq = lane & 15;

  stage_gemm(A, As, m0, 0, tid, wid);
  stage_gemm(Bm, Bs, n0, 0, tid, wid);
  stage_gemm(A, As + 4096, m0, 32, tid, wid);
  stage_gemm(Bm, Bs + 4096, n0, 32, tid, wid);
  int buf = 0;
  for (int k0 = 0; k0 < 1024; k0 += 32) {
    if (k0 + 32 < 1024) WAIT_VM4; else WAIT_VM0;
    BARRIER;
    const unsigned short* Ab = As + buf * 4096;
    const unsigned short* Bb = Bs + buf * 4096;
    U8 af[4], bfr[4];
#pragma unroll
    for (int f = 0; f < 4; ++f) {
      af[f].u  = *(const u16x8*)&Ab[(wr * 64 + f * 16 + lq) * 32 + ((g ^ (lq & 3)) * 8)];
      bfr[f].u = *(const u16x8*)&Bb[(wc * 64 + f * 16 + lq) * 32 + ((g ^ (lq & 3)) * 8)];
    }
#pragma unroll
    for (int i = 0; i < 4; ++i)
#pragma unroll
      for (int j = 0; j < 4; ++j)
        acc[i][j] = __builtin_amdgcn_mfma_f32_16x16x32_bf16(af[i].b, bfr[j].b,
                                                            acc[i][j], 0, 0, 0);
    WAIT_LGKM;
    BARRIER;
    if (k0 + 64 < 1024) {
      stage_gemm(A, As + buf * 4096, m0, k0 + 64, tid, wid);
      stage_gemm(Bm, Bs + buf * 4096, n0, k0 + 64, tid, wid);
    }
    buf ^= 1;
  }
}

// ---------------- kernel 1: QKV projection ----------------
__global__ __launch_bounds__(256) void k_gemm_qkv(
    const unsigned short* __restrict__ xb,
    const unsigned short* __restrict__ Wqt, const unsigned short* __restrict__ Wkt,
    const unsigned short* __restrict__ Wvt,
    const float* __restrict__ bq, const float* __restrict__ bk,
    const float* __restrict__ bv,
    unsigned short* __restrict__ Qo, unsigned short* __restrict__ Ko,
    unsigned short* __restrict__ Vto) {
  __shared__ unsigned short As[2 * 4096];
  __shared__ unsigned short Bs[2 * 4096];
  const int z = blockIdx.z;
  const unsigned short* Bm = (z == 0) ? Wqt : (z == 1) ? Wkt : Wvt;
  const float* bias = (z == 0) ? bq : (z == 1) ? bk : bv;

  f32x4 acc[4][4];
#pragma unroll
  for (int i = 0; i < 4; ++i)
#pragma unroll
    for (int j = 0; j < 4; ++j) acc[i][j] = f32x4{0.f, 0.f, 0.f, 0.f};

  const int m0 = blockIdx.x * 128, n0 = blockIdx.y * 128;
  gemm_main(xb, Bm, As, Bs, m0, n0, acc);

  const int lane = threadIdx.x & 63, wid = threadIdx.x >> 6;
  const int wr = wid >> 1, wc = wid & 1;
  const int g = lane >> 4, lq = lane & 15;
  unsigned short* dstQK = (z == 0) ? Qo : Ko;
#pragma unroll
  for (int j = 0; j < 4; ++j) {
    int col = n0 + wc * 64 + j * 16 + lq;
    float bv_ = bias[col];
    int h = col >> 6, d = col & 63;
#pragma unroll
    for (int i = 0; i < 4; ++i) {
#pragma unroll
      for (int r = 0; r < 4; ++r) {
        int row = m0 + wr * 64 + i * 16 + g * 4 + r;
        int b = row >> 11, s = row & 2047;
        unsigned short hv = f2bf(acc[i][j][r] + bv_);
        if (z < 2)
          dstQK[(((size_t)(b * 16 + h)) * 2048 + s) * 64 + d] = hv;
        else
          Vto[(((size_t)(b * 16 + h)) * 64 + d) * 2048 + s] = hv;
      }
    }
  }
}

// ---------------- kernel 3: output projection (fp32 out + bias) ----------------
__global__ __launch_bounds__(256) void k_gemm_out(
    const unsigned short* __restrict__ Ob, const unsigned short* __restrict__ Wot,
    const float* __restrict__ bo, float* __restrict__ out) {
  __shared__ unsigned short As[2 * 4096];
  __shared__ unsigned short Bs[2 * 4096];
  f32x4 acc[4][4];
#pragma unroll
  for (int i = 0; i < 4; ++i)
#pragma unroll
    for (int j = 0; j < 4; ++j) acc[i][j] = f32x4{0.f, 0.f, 0.f, 0.f};

  const int m0 = blockIdx.x * 128, n0 = blockIdx.y * 128;
  gemm_main(Ob, Wot, As, Bs, m0, n0, acc);

  const int lane = threadIdx.x & 63, wid = threadIdx.x >> 6;
  const int wr = wid >> 1, wc = wid & 1;
  const int g = lane >> 4, lq = lane & 15;
#pragma unroll
  for (int j = 0; j < 4; ++j) {
    int col = n0 + wc * 64 + j * 16 + lq;
    float bv_ = bo[col];
#pragma unroll
    for (int i = 0; i < 4; ++i)
#pragma unroll
      for (int r = 0; r < 4; ++r) {
        int row = m0 + wr * 64 + i * 16 + g * 4 + r;
        out[(size_t)row * 1024 + col] = acc[i][j][r] + bv_;
      }
  }
}

// ---------------- kernel 2: flash attention v6 ------------------------------
// 256 blocks (1/CU), XCD-chunked: XCD x owns bh = 4x..4x+3. Each block handles
// the q-block PAIR (qb, 15-qb) sequentially -> uniform 34 k-tiles per block.
// Block 256 thr (4 waves), wave owns 32 q rows (groups A/B). K/V 64-tile LDS
// double-buffer staged by gload16 (4 loads/thread/tile), counted vmcnt(4).
DI void softmax_step(f32x4 sacc[4], float& m, float& l, f32x4 oacc[4],
                     unsigned int pk[4][2], int kk0, int qrow, int g) {
  float vmax = -1e30f;
#pragma unroll
  for (int c = 0; c < 4; ++c)
#pragma unroll
    for (int r = 0; r < 4; ++r) {
      int k = kk0 + c * 16 + g * 4 + r;
      float sv = fabsf(sacc[c][r] * 0.125f);
      sv = (k <= qrow) ? sv : -1e30f;
      sacc[c][r] = sv;
      vmax = fmaxf(vmax, sv);
    }
  vmax = fmaxf(vmax, __shfl_xor(vmax, 16, 64));
  vmax = fmaxf(vmax, __shfl_xor(vmax, 32, 64));
  float mn = fmaxf(m, vmax);
  float alpha = __expf(m - mn);
  m = mn;
  float s = 0.f;
#pragma unroll
  for (int c = 0; c < 4; ++c)
#pragma unroll
    for (int r = 0; r < 4; ++r) {
      float p = __expf(sacc[c][r] - mn);
      sacc[c][r] = p;
      s += p;
    }
  s += __shfl_xor(s, 16, 64);
  s += __shfl_xor(s, 32, 64);
  l = l * alpha + s;
#pragma unroll
  for (int c = 0; c < 4; ++c)
#pragma unroll
    for (int r = 0; r < 4; ++r) oacc[c][r] *= alpha;
#pragma unroll
  for (int c = 0; c < 4; ++c) {
    pk[c][0] = pack2(sacc[c][0], sacc[c][1]);
    pk[c][1] = pack2(sacc[c][2], sacc[c][3]);
  }
}

__global__ __launch_bounds__(256) void k_flash(
    const unsigned short* __restrict__ Q, const unsigned short* __restrict__ Km,
    const unsigned short* __restrict__ Vt, unsigned short* __restrict__ O) {
  const int tid = threadIdx.x;
  const int lane = tid & 63, wid = tid >> 6;
  const int g = lane >> 4, lq = lane & 15;
  const int bid = blockIdx.x;            // 256 blocks
  const int xcd = bid & 7, idx = bid >> 3;
  const int bh = xcd * 4 + (idx >> 3);   // 4 bh per XCD
  const int pairidx = idx & 7;
  const int b = bh >> 4, h = bh & 15;
  const size_t qkbase = (size_t)bh * 2048 * 64;
  const size_t vbase = (size_t)bh * 64 * 2048;

  __shared__ unsigned short Ks[2][64 * 64];
  __shared__ unsigned short Vs[2][64 * 64];

  // stage(buf, t): K tile rows=k, V tile rows=dv; 4 gload16/thread total
  auto stage = [&](int bf, int t) {
    const int kk0 = t * 64;
#pragma unroll
    for (int i = 0; i < 2; ++i) {
      int T = i * 256 + tid;
      int row = T >> 3, ch = T & 7;
      int sch = ch ^ (row & 7);
      gload16(&Km[qkbase + (size_t)(kk0 + row) * 64 + sch * 8],
              &Ks[bf][(i * 2048 + wid * 512)]);
      gload16(&Vt[vbase + (size_t)row * 2048 + kk0 + sch * 8],
              &Vs[bf][(i * 2048 + wid * 512)]);
    }
  };

  for (int ph = 0; ph < 2; ++ph) {
    const int qb = ph ? (15 - pairidx) : pairidx;
    const int q0 = qb * 128;
    const int qrowA = q0 + wid * 32 + lq;
    const int qrowB = qrowA + 16;

    U8 aq0A, aq1A, aq0B, aq1B;
    {
      const unsigned short* qp = &Q[qkbase + (size_t)qrowA * 64 + g * 8];
      aq0A.u = *(const u16x8*)qp;
      aq1A.u = *(const u16x8*)(qp + 32);
      const unsigned short* qp2 = &Q[qkbase + (size_t)qrowB * 64 + g * 8];
      aq0B.u = *(const u16x8*)qp2;
      aq1B.u = *(const u16x8*)(qp2 + 32);
    }
    float mA = -1e30f, lA = 0.f, mB = -1e30f, lB = 0.f;
    f32x4 oaccA[4], oaccB[4];
#pragma unroll
    for (int c = 0; c < 4; ++c) {
      oaccA[c] = f32x4{0.f, 0.f, 0.f, 0.f};
      oaccB[c] = f32x4{0.f, 0.f, 0.f, 0.f};
    }

    const int nt = 2 * qb + 2;
    stage(0, 0);
    stage(1, 1);
    int buf = 0;
    for (int t = 0; t < nt; ++t) {
      const int kk0 = t * 64;
      if (t + 1 < nt) WAIT_VM4; else WAIT_VM0;
      BARRIER;
      // ---- QK^T: A = K frags from LDS, B = Q frags (A,B share K reads)
      f32x4 saccA[4], saccB[4];
#pragma unroll
      for (int c = 0; c < 4; ++c) {
        U8 kf0, kf1;
        kf0.u = *(const u16x8*)&Ks[buf][(c * 16 + lq) * 64 + (((0 * 4 + g) ^ (lq & 7)) * 8)];
        kf1.u = *(const u16x8*)&Ks[buf][(c * 16 + lq) * 64 + (((1 * 4 + g) ^ (lq & 7)) * 8)];
        saccA[c] = __builtin_amdgcn_mfma_f32_16x16x32_bf16(kf0.b, aq0A.b,
                                                           f32x4{0.f, 0.f, 0.f, 0.f}, 0, 0, 0);
        saccA[c] = __builtin_amdgcn_mfma_f32_16x16x32_bf16(kf1.b, aq1A.b, saccA[c], 0, 0, 0);
        saccB[c] = __builtin_amdgcn_mfma_f32_16x16x32_bf16(kf0.b, aq0B.b,
                                                           f32x4{0.f, 0.f, 0.f, 0.f}, 0, 0, 0);
        saccB[c] = __builtin_amdgcn_mfma_f32_16x16x32_bf16(kf1.b, aq1B.b, saccB[c], 0, 0, 0);
      }
      // ---- softmax (two independent chains)
      unsigned int pkA[4][2], pkB[4][2];
      softmax_step(saccA, mA, lA, oaccA, pkA, kk0, qrowA, g);
      softmax_step(saccB, mB, lB, oaccB, pkB, kk0, qrowB, g);
      // ---- re-fragment P; PV: A = V^T frags from LDS (shared by A,B)
#pragma unroll
      for (int hh = 0; hh < 2; ++hh) {
        PB pbA, pbB;
#pragma unroll
        for (int w2 = 0; w2 < 4; ++w2) {
          int src = (((g & 1) * 2 + (w2 >> 1)) << 4) + lq;
          unsigned int loA = __shfl(pkA[hh * 2 + 0][w2 & 1], src, 64);
          unsigned int hiA = __shfl(pkA[hh * 2 + 1][w2 & 1], src, 64);
          pbA.w[w2] = (g >> 1) ? hiA : loA;
          unsigned int loB = __shfl(pkB[hh * 2 + 0][w2 & 1], src, 64);
          unsigned int hiB = __shfl(pkB[hh * 2 + 1][w2 & 1], src, 64);
          pbB.w[w2] = (g >> 1) ? hiB : loB;
        }
#pragma unroll
        for (int c = 0; c < 4; ++c) {
          U8 vf;
          vf.u = *(const u16x8*)&Vs[buf][(c * 16 + lq) * 64 + (((hh * 4 + g) ^ (lq & 7)) * 8)];
          oaccA[c] = __builtin_amdgcn_mfma_f32_16x16x32_bf16(vf.b, pbA.b, oaccA[c], 0, 0, 0);
          oaccB[c] = __builtin_amdgcn_mfma_f32_16x16x32_bf16(vf.b, pbB.b, oaccB[c], 0, 0, 0);
        }
      }
      WAIT_LGKM;
      BARRIER;
      if (t + 2 < nt) stage(buf, t + 2);
      buf ^= 1;
    }
    // ---- epilogue: O[b][s=qrow][h*64+dv], dv = c*16 + g*4 + r
    float invA = 1.0f / lA, invB = 1.0f / lB;
#pragma unroll
    for (int c = 0; c < 4; ++c) {
      u16x4 ovA, ovB;
#pragma unroll
      for (int r = 0; r < 4; ++r) {
        ovA[r] = f2bf(oaccA[c][r] * invA);
        ovB[r] = f2bf(oaccB[c][r] * invB);
      }
      *(u16x4*)&O[((size_t)(b * 2048 + qrowA)) * 1024 + h * 64 + c * 16 + g * 4] = ovA;
      *(u16x4*)&O[((size_t)(b * 2048 + qrowB)) * 1024 + h * 64 + c * 16 + g * 4] = ovB;
    }
  }
}

// ---------------- launch ----------------
extern "C" void kernel_launch(void* const* d_in, const int* in_sizes, int n_in,
                              void* d_out, int out_size, void* d_ws, size_t ws_size,
                              hipStream_t stream) {
  const float* x  = (const float*)d_in[0];
  const float* Wq = (const float*)d_in[1];
  const float* bq = (const float*)d_in[2];
  const float* Wk = (const float*)d_in[3];
  const float* bk = (const float*)d_in[4];
  const float* Wv = (const float*)d_in[5];
  const float* bv = (const float*)d_in[6];
  const float* Wo = (const float*)d_in[7];
  const float* bo = (const float*)d_in[8];
  float* out = (float*)d_out;

  char* ws = (char*)d_ws;
  const size_t MB = 1024 * 1024;
  unsigned short* xb   = (unsigned short*)(ws + 0 * MB);   // 8 MB
  unsigned short* Wqt  = (unsigned short*)(ws + 8 * MB);   // 2 MB
  unsigned short* Wkt  = (unsigned short*)(ws + 10 * MB);  // 2 MB
  unsigned short* Wvt  = (unsigned short*)(ws + 12 * MB);  // 2 MB
  unsigned short* Wot  = (unsigned short*)(ws + 14 * MB);  // 2 MB
  unsigned short* Qws  = (unsigned short*)(ws + 16 * MB);  // 8 MB
  unsigned short* Kws  = (unsigned short*)(ws + 24 * MB);  // 8 MB
  unsigned short* Vtws = (unsigned short*)(ws + 32 * MB);  // 8 MB
  unsigned short* Ows  = (unsigned short*)(ws + 40 * MB);  // 8 MB

  k_conv_x<<<4096, 256, 0, stream>>>(x, xb);
  k_transpose<<<dim3(32, 32, 4), dim3(32, 8), 0, stream>>>(Wq, Wk, Wv, Wo,
                                                           Wqt, Wkt, Wvt, Wot);
  k_gemm_qkv<<<dim3(32, 8, 3), 256, 0, stream>>>(xb, Wqt, Wkt, Wvt, bq, bk, bv,
                                                 Qws, Kws, Vtws);
  k_flash<<<256, 256, 0, stream>>>(Qws, Kws, Vtws, Ows);
  k_gemm_out<<<dim3(32, 8), 256, 0, stream>>>(Ows, Wot, bo, out);
}

// Round 7
// 143.289 us; speedup vs baseline: 2.1606x; 1.1344x over previous
//
#include <hip/hip_runtime.h>

// MHA: B=2, S=2048, D=1024, H=16, DK=DV=64
// out = softmax(mask(|QK^T/8|)) V, then output projection.
// All matmuls in bf16 MFMA (16x16x32), fp32 accumulate.
// Round 7: flash = 512 uniform blocks (pair qb,31-qb; 33 tiles each), 1 softmax
// group/wave -> 2 waves/SIMD; exp2-domain softmax; setprio around MFMA.
// GEMMs reverted to round-5 __syncthreads double-buffer (counted-vmcnt hurt).

#define DI __device__ __forceinline__

typedef __bf16 bf16x8 __attribute__((ext_vector_type(8)));
typedef float f32x4 __attribute__((ext_vector_type(4)));
typedef unsigned short u16x8 __attribute__((ext_vector_type(8)));
typedef unsigned short u16x4 __attribute__((ext_vector_type(4)));

union U8 { u16x8 u; bf16x8 b; };
union PB { unsigned int w[4]; u16x8 u; bf16x8 b; };

typedef const __attribute__((address_space(1))) unsigned int* gas_p;
typedef __attribute__((address_space(3))) unsigned int* las_p;

DI void gload16(const unsigned short* g, unsigned short* l) {
  __builtin_amdgcn_global_load_lds((gas_p)(const void*)g, (las_p)(void*)l, 16, 0, 0);
}

#define WAIT_VM4  asm volatile("s_waitcnt vmcnt(4)" ::: "memory")
#define WAIT_VM0  asm volatile("s_waitcnt vmcnt(0)" ::: "memory")
#define WAIT_LGKM asm volatile("s_waitcnt lgkmcnt(0)" ::: "memory")
#define BARRIER   __builtin_amdgcn_s_barrier()

DI unsigned short f2bf(float f) {            // round-to-nearest-even
  unsigned int u = __float_as_uint(f);
  u += 0x7FFFu + ((u >> 16) & 1u);
  return (unsigned short)(u >> 16);
}
DI unsigned int pack2(float a, float b) {
  return (unsigned int)f2bf(a) | ((unsigned int)f2bf(b) << 16);
}

// ---------------- kernel 0a: x fp32 -> bf16 ----------------
__global__ __launch_bounds__(256) void k_conv_x(const float* __restrict__ x,
                                                unsigned short* __restrict__ xb) {
  size_t i = ((size_t)blockIdx.x * 256 + threadIdx.x) * 4;
  float4 v = *(const float4*)(x + i);
  u16x4 o;
  o[0] = f2bf(v.x); o[1] = f2bf(v.y); o[2] = f2bf(v.z); o[3] = f2bf(v.w);
  *(u16x4*)(xb + i) = o;
}

// ---------------- kernel 0b: W[k][n] f32 -> Wt[n][k] bf16 (1024x1024) ----------------
__global__ __launch_bounds__(256) void k_transpose(
    const float* __restrict__ W0, const float* __restrict__ W1,
    const float* __restrict__ W2, const float* __restrict__ W3,
    unsigned short* __restrict__ T0, unsigned short* __restrict__ T1,
    unsigned short* __restrict__ T2, unsigned short* __restrict__ T3) {
  const int z = blockIdx.z;
  const float* W = (z == 0) ? W0 : (z == 1) ? W1 : (z == 2) ? W2 : W3;
  unsigned short* T = (z == 0) ? T0 : (z == 1) ? T1 : (z == 2) ? T2 : T3;
  __shared__ unsigned short buf[32][33];
  const int k0 = blockIdx.x * 32, n0 = blockIdx.y * 32;
  const int tx = threadIdx.x, ty = threadIdx.y;   // (32, 8)
#pragma unroll
  for (int j = 0; j < 4; ++j) {
    int r = ty + j * 8;
    buf[r][tx] = f2bf(W[(size_t)(k0 + r) * 1024 + n0 + tx]);
  }
  __syncthreads();
#pragma unroll
  for (int j = 0; j < 4; ++j) {
    int c = ty + j * 8;
    T[(size_t)(n0 + c) * 1024 + k0 + tx] = buf[tx][c];
  }
}

// ---------------- shared GEMM main loop (round-5 form: gload_lds + dbuf) ------
// C(128x128) = A(128xK) * Wt(128xK)^T, K=1024, bf16 MFMA 16x16x32, BK=32.
// LDS tile [128][32] linear; source pre-swizzled chunk ^= row&3.
DI void stage_gemm(const unsigned short* __restrict__ src, unsigned short* dst,
                   int row0, int k0, int tid, int wid) {
#pragma unroll
  for (int i = 0; i < 2; ++i) {
    int T = i * 256 + tid;
    int row = T >> 2, ch = T & 3;
    int sch = ch ^ (row & 3);
    gload16(&src[(size_t)(row0 + row) * 1024 + k0 + sch * 8],
            &dst[(i * 256 + wid * 64) * 8]);
  }
}

DI void gemm_main(const unsigned short* __restrict__ A,
                  const unsigned short* __restrict__ Bm,
                  unsigned short* As, unsigned short* Bs,
                  int m0, int n0, f32x4 acc[4][4]) {
  const int tid = threadIdx.x;
  const int lane = tid & 63, wid = tid >> 6;
  const int wr = wid >> 1, wc = wid & 1;
  const int g = lane >> 4, lq = lane & 15;

  stage_gemm(A, As, m0, 0, tid, wid);
  stage_gemm(Bm, Bs, n0, 0, tid, wid);
  __syncthreads();
  int buf = 0;
  for (int k0 = 0; k0 < 1024; k0 += 32) {
    if (k0 + 32 < 1024) {
      stage_gemm(A, As + (buf ^ 1) * 4096, m0, k0 + 32, tid, wid);
      stage_gemm(Bm, Bs + (buf ^ 1) * 4096, n0, k0 + 32, tid, wid);
    }
    const unsigned short* Ab = As + buf * 4096;
    const unsigned short* Bb = Bs + buf * 4096;
    U8 af[4], bfr[4];
#pragma unroll
    for (int f = 0; f < 4; ++f) {
      af[f].u  = *(const u16x8*)&Ab[(wr * 64 + f * 16 + lq) * 32 + ((g ^ (lq & 3)) * 8)];
      bfr[f].u = *(const u16x8*)&Bb[(wc * 64 + f * 16 + lq) * 32 + ((g ^ (lq & 3)) * 8)];
    }
#pragma unroll
    for (int i = 0; i < 4; ++i)
#pragma unroll
      for (int j = 0; j < 4; ++j)
        acc[i][j] = __builtin_amdgcn_mfma_f32_16x16x32_bf16(af[i].b, bfr[j].b,
                                                            acc[i][j], 0, 0, 0);
    __syncthreads();
    buf ^= 1;
  }
}

// ---------------- kernel 1: QKV projection ----------------
__global__ __launch_bounds__(256) void k_gemm_qkv(
    const unsigned short* __restrict__ xb,
    const unsigned short* __restrict__ Wqt, const unsigned short* __restrict__ Wkt,
    const unsigned short* __restrict__ Wvt,
    const float* __restrict__ bq, const float* __restrict__ bk,
    const float* __restrict__ bv,
    unsigned short* __restrict__ Qo, unsigned short* __restrict__ Ko,
    unsigned short* __restrict__ Vto) {
  __shared__ unsigned short As[2 * 4096];
  __shared__ unsigned short Bs[2 * 4096];
  const int z = blockIdx.z;
  const unsigned short* Bm = (z == 0) ? Wqt : (z == 1) ? Wkt : Wvt;
  const float* bias = (z == 0) ? bq : (z == 1) ? bk : bv;

  f32x4 acc[4][4];
#pragma unroll
  for (int i = 0; i < 4; ++i)
#pragma unroll
    for (int j = 0; j < 4; ++j) acc[i][j] = f32x4{0.f, 0.f, 0.f, 0.f};

  const int m0 = blockIdx.x * 128, n0 = blockIdx.y * 128;
  gemm_main(xb, Bm, As, Bs, m0, n0, acc);

  const int lane = threadIdx.x & 63, wid = threadIdx.x >> 6;
  const int wr = wid >> 1, wc = wid & 1;
  const int g = lane >> 4, lq = lane & 15;
  unsigned short* dstQK = (z == 0) ? Qo : Ko;
#pragma unroll
  for (int j = 0; j < 4; ++j) {
    int col = n0 + wc * 64 + j * 16 + lq;
    float bv_ = bias[col];
    int h = col >> 6, d = col & 63;
#pragma unroll
    for (int i = 0; i < 4; ++i) {
#pragma unroll
      for (int r = 0; r < 4; ++r) {
        int row = m0 + wr * 64 + i * 16 + g * 4 + r;
        int b = row >> 11, s = row & 2047;
        unsigned short hv = f2bf(acc[i][j][r] + bv_);
        if (z < 2)
          dstQK[(((size_t)(b * 16 + h)) * 2048 + s) * 64 + d] = hv;
        else
          Vto[(((size_t)(b * 16 + h)) * 64 + d) * 2048 + s] = hv;
      }
    }
  }
}

// ---------------- kernel 3: output projection (fp32 out + bias) ----------------
__global__ __launch_bounds__(256) void k_gemm_out(
    const unsigned short* __restrict__ Ob, const unsigned short* __restrict__ Wot,
    const float* __restrict__ bo, float* __restrict__ out) {
  __shared__ unsigned short As[2 * 4096];
  __shared__ unsigned short Bs[2 * 4096];
  f32x4 acc[4][4];
#pragma unroll
  for (int i = 0; i < 4; ++i)
#pragma unroll
    for (int j = 0; j < 4; ++j) acc[i][j] = f32x4{0.f, 0.f, 0.f, 0.f};

  const int m0 = blockIdx.x * 128, n0 = blockIdx.y * 128;
  gemm_main(Ob, Wot, As, Bs, m0, n0, acc);

  const int lane = threadIdx.x & 63, wid = threadIdx.x >> 6;
  const int wr = wid >> 1, wc = wid & 1;
  const int g = lane >> 4, lq = lane & 15;
#pragma unroll
  for (int j = 0; j < 4; ++j) {
    int col = n0 + wc * 64 + j * 16 + lq;
    float bv_ = bo[col];
#pragma unroll
    for (int i = 0; i < 4; ++i)
#pragma unroll
      for (int r = 0; r < 4; ++r) {
        int row = m0 + wr * 64 + i * 16 + g * 4 + r;
        out[(size_t)row * 1024 + col] = acc[i][j][r] + bv_;
      }
  }
}

// ---------------- kernel 2: flash attention v7 ------------------------------
// 512 blocks (2/CU -> 2 waves/SIMD), XCD-chunked (4 bh/XCD). Each block: pair
// (qb, 31-qb) of 64-row q-blocks -> uniform 33 k-tiles. 4 waves, wave owns 16
// q rows (one softmax group). K/V 64-tile LDS dbuf, gload16, counted vmcnt(4).
// exp2-domain softmax: sv = |s| * (0.125*log2e); p = exp2(sv - m2).
DI void softmax_step(f32x4 sacc[4], float& m, float& l, f32x4 oacc[4],
                     unsigned int pk[4][2], int kk0, int qrow, int g) {
  const float SC = 0.18033688011112042f;   // 0.125 * log2(e)
  float vmax = -1e30f;
#pragma unroll
  for (int c = 0; c < 4; ++c)
#pragma unroll
    for (int r = 0; r < 4; ++r) {
      int k = kk0 + c * 16 + g * 4 + r;
      float sv = fabsf(sacc[c][r]) * SC;
      sv = (k <= qrow) ? sv : -1e30f;
      sacc[c][r] = sv;
      vmax = fmaxf(vmax, sv);
    }
  vmax = fmaxf(vmax, __shfl_xor(vmax, 16, 64));
  vmax = fmaxf(vmax, __shfl_xor(vmax, 32, 64));
  float mn = fmaxf(m, vmax);
  float alpha = exp2f(m - mn);
  m = mn;
  float s = 0.f;
#pragma unroll
  for (int c = 0; c < 4; ++c)
#pragma unroll
    for (int r = 0; r < 4; ++r) {
      float p = exp2f(sacc[c][r] - mn);
      sacc[c][r] = p;
      s += p;
    }
  s += __shfl_xor(s, 16, 64);
  s += __shfl_xor(s, 32, 64);
  l = l * alpha + s;
#pragma unroll
  for (int c = 0; c < 4; ++c)
#pragma unroll
    for (int r = 0; r < 4; ++r) oacc[c][r] *= alpha;
#pragma unroll
  for (int c = 0; c < 4; ++c) {
    pk[c][0] = pack2(sacc[c][0], sacc[c][1]);
    pk[c][1] = pack2(sacc[c][2], sacc[c][3]);
  }
}

__global__ __launch_bounds__(256) void k_flash(
    const unsigned short* __restrict__ Q, const unsigned short* __restrict__ Km,
    const unsigned short* __restrict__ Vt, unsigned short* __restrict__ O) {
  const int tid = threadIdx.x;
  const int lane = tid & 63, wid = tid >> 6;
  const int g = lane >> 4, lq = lane & 15;
  const int bid = blockIdx.x;            // 512 blocks
  const int xcd = bid & 7, idx = bid >> 3;  // 64 per XCD
  const int bh = xcd * 4 + (idx >> 4);      // 4 bh per XCD
  const int pairidx = idx & 15;
  const int b = bh >> 4, h = bh & 15;
  const size_t qkbase = (size_t)bh * 2048 * 64;
  const size_t vbase = (size_t)bh * 64 * 2048;

  __shared__ unsigned short Ks[2][64 * 64];
  __shared__ unsigned short Vs[2][64 * 64];

  // stage(buf, t): K tile rows=k, V tile rows=dv; 4 gload16/thread total
  auto stage = [&](int bf, int t) {
    const int kk0 = t * 64;
#pragma unroll
    for (int i = 0; i < 2; ++i) {
      int T = i * 256 + tid;
      int row = T >> 3, ch = T & 7;
      int sch = ch ^ (row & 7);
      gload16(&Km[qkbase + (size_t)(kk0 + row) * 64 + sch * 8],
              &Ks[bf][(i * 2048 + wid * 512)]);
      gload16(&Vt[vbase + (size_t)row * 2048 + kk0 + sch * 8],
              &Vs[bf][(i * 2048 + wid * 512)]);
    }
  };

  for (int ph = 0; ph < 2; ++ph) {
    const int qb = ph ? (31 - pairidx) : pairidx;
    const int q0 = qb * 64;
    const int qrow = q0 + wid * 16 + lq;

    U8 aq0, aq1;
    {
      const unsigned short* qp = &Q[qkbase + (size_t)qrow * 64 + g * 8];
      aq0.u = *(const u16x8*)qp;
      aq1.u = *(const u16x8*)(qp + 32);
    }
    float m = -1e30f, l = 0.f;
    f32x4 oacc[4];
#pragma unroll
    for (int c = 0; c < 4; ++c) oacc[c] = f32x4{0.f, 0.f, 0.f, 0.f};

    const int nt = qb + 1;
    stage(0, 0);
    if (nt > 1) stage(1, 1);
    int buf = 0;
    for (int t = 0; t < nt; ++t) {
      const int kk0 = t * 64;
      if (t + 1 < nt) WAIT_VM4; else WAIT_VM0;
      BARRIER;
      // ---- QK^T: A = K frags from LDS, B = Q frag
      f32x4 sacc[4];
      __builtin_amdgcn_s_setprio(1);
#pragma unroll
      for (int c = 0; c < 4; ++c) {
        U8 kf0, kf1;
        kf0.u = *(const u16x8*)&Ks[buf][(c * 16 + lq) * 64 + (((0 * 4 + g) ^ (lq & 7)) * 8)];
        kf1.u = *(const u16x8*)&Ks[buf][(c * 16 + lq) * 64 + (((1 * 4 + g) ^ (lq & 7)) * 8)];
        sacc[c] = __builtin_amdgcn_mfma_f32_16x16x32_bf16(kf0.b, aq0.b,
                                                          f32x4{0.f, 0.f, 0.f, 0.f}, 0, 0, 0);
        sacc[c] = __builtin_amdgcn_mfma_f32_16x16x32_bf16(kf1.b, aq1.b, sacc[c], 0, 0, 0);
      }
      __builtin_amdgcn_s_setprio(0);
      // ---- softmax (lane owns q = qrow)
      unsigned int pk[4][2];
      softmax_step(sacc, m, l, oacc, pk, kk0, qrow, g);
      // ---- re-fragment P; PV: A = V^T frags from LDS
      __builtin_amdgcn_s_setprio(1);
#pragma unroll
      for (int hh = 0; hh < 2; ++hh) {
        PB pb;
#pragma unroll
        for (int w2 = 0; w2 < 4; ++w2) {
          int src = (((g & 1) * 2 + (w2 >> 1)) << 4) + lq;
          unsigned int lo = __shfl(pk[hh * 2 + 0][w2 & 1], src, 64);
          unsigned int hi = __shfl(pk[hh * 2 + 1][w2 & 1], src, 64);
          pb.w[w2] = (g >> 1) ? hi : lo;
        }
#pragma unroll
        for (int c = 0; c < 4; ++c) {
          U8 vf;
          vf.u = *(const u16x8*)&Vs[buf][(c * 16 + lq) * 64 + (((hh * 4 + g) ^ (lq & 7)) * 8)];
          oacc[c] = __builtin_amdgcn_mfma_f32_16x16x32_bf16(vf.b, pb.b, oacc[c], 0, 0, 0);
        }
      }
      __builtin_amdgcn_s_setprio(0);
      WAIT_LGKM;
      BARRIER;
      if (t + 2 < nt) stage(buf, t + 2);
      buf ^= 1;
    }
    // ---- epilogue: O[b][s=qrow][h*64+dv], dv = c*16 + g*4 + r
    float inv_l = 1.0f / l;
#pragma unroll
    for (int c = 0; c < 4; ++c) {
      u16x4 ov;
#pragma unroll
      for (int r = 0; r < 4; ++r) ov[r] = f2bf(oacc[c][r] * inv_l);
      *(u16x4*)&O[((size_t)(b * 2048 + qrow)) * 1024 + h * 64 + c * 16 + g * 4] = ov;
    }
  }
}

// ---------------- launch ----------------
extern "C" void kernel_launch(void* const* d_in, const int* in_sizes, int n_in,
                              void* d_out, int out_size, void* d_ws, size_t ws_size,
                              hipStream_t stream) {
  const float* x  = (const float*)d_in[0];
  const float* Wq = (const float*)d_in[1];
  const float* bq = (const float*)d_in[2];
  const float* Wk = (const float*)d_in[3];
  const float* bk = (const float*)d_in[4];
  const float* Wv = (const float*)d_in[5];
  const float* bv = (const float*)d_in[6];
  const float* Wo = (const float*)d_in[7];
  const float* bo = (const float*)d_in[8];
  float* out = (float*)d_out;

  char* ws = (char*)d_ws;
  const size_t MB = 1024 * 1024;
  unsigned short* xb   = (unsigned short*)(ws + 0 * MB);   // 8 MB
  unsigned short* Wqt  = (unsigned short*)(ws + 8 * MB);   // 2 MB
  unsigned short* Wkt  = (unsigned short*)(ws + 10 * MB);  // 2 MB
  unsigned short* Wvt  = (unsigned short*)(ws + 12 * MB);  // 2 MB
  unsigned short* Wot  = (unsigned short*)(ws + 14 * MB);  // 2 MB
  unsigned short* Qws  = (unsigned short*)(ws + 16 * MB);  // 8 MB
  unsigned short* Kws  = (unsigned short*)(ws + 24 * MB);  // 8 MB
  unsigned short* Vtws = (unsigned short*)(ws + 32 * MB);  // 8 MB
  unsigned short* Ows  = (unsigned short*)(ws + 40 * MB);  // 8 MB

  k_conv_x<<<4096, 256, 0, stream>>>(x, xb);
  k_transpose<<<dim3(32, 32, 4), dim3(32, 8), 0, stream>>>(Wq, Wk, Wv, Wo,
                                                           Wqt, Wkt, Wvt, Wot);
  k_gemm_qkv<<<dim3(32, 8, 3), 256, 0, stream>>>(xb, Wqt, Wkt, Wvt, bq, bk, bv,
                                                 Qws, Kws, Vtws);
  k_flash<<<512, 256, 0, stream>>>(Qws, Kws, Vtws, Ows);
  k_gemm_out<<<dim3(32, 8), 256, 0, stream>>>(Ows, Wot, bo, out);
}

// Round 8
// 126.451 us; speedup vs baseline: 2.4483x; 1.1332x over previous
//
#include <hip/hip_runtime.h>

// MHA: B=2, S=2048, D=1024, H=16, DK=DV=64
// out = softmax(mask(|QK^T/8|)) V, then output projection.
// All matmuls in bf16 MFMA (16x16x32), fp32 accumulate.
// Round 8: flash softmax with FIXED m=0 (|s|*0.125*log2e < 1 for this data;
// exp2 overflow needs |s|>660 -> 200x margin): no running max, no rescale,
// deferred l-reduction (epilogue only), causal mask on diagonal tile only,
// v_cvt_pk_bf16_f32 packing. GEMMs unchanged (round-5/7 dbuf form).

#define DI __device__ __forceinline__

typedef __bf16 bf16x8 __attribute__((ext_vector_type(8)));
typedef float f32x4 __attribute__((ext_vector_type(4)));
typedef unsigned short u16x8 __attribute__((ext_vector_type(8)));
typedef unsigned short u16x4 __attribute__((ext_vector_type(4)));

union U8 { u16x8 u; bf16x8 b; };
union PB { unsigned int w[4]; u16x8 u; bf16x8 b; };

typedef const __attribute__((address_space(1))) unsigned int* gas_p;
typedef __attribute__((address_space(3))) unsigned int* las_p;

DI void gload16(const unsigned short* g, unsigned short* l) {
  __builtin_amdgcn_global_load_lds((gas_p)(const void*)g, (las_p)(void*)l, 16, 0, 0);
}

#define WAIT_VM4  asm volatile("s_waitcnt vmcnt(4)" ::: "memory")
#define WAIT_VM0  asm volatile("s_waitcnt vmcnt(0)" ::: "memory")
#define WAIT_LGKM asm volatile("s_waitcnt lgkmcnt(0)" ::: "memory")
#define BARRIER   __builtin_amdgcn_s_barrier()

DI unsigned short f2bf(float f) {            // round-to-nearest-even
  unsigned int u = __float_as_uint(f);
  u += 0x7FFFu + ((u >> 16) & 1u);
  return (unsigned short)(u >> 16);
}

// ---------------- kernel 0a: x fp32 -> bf16 ----------------
__global__ __launch_bounds__(256) void k_conv_x(const float* __restrict__ x,
                                                unsigned short* __restrict__ xb) {
  size_t i = ((size_t)blockIdx.x * 256 + threadIdx.x) * 4;
  float4 v = *(const float4*)(x + i);
  u16x4 o;
  o[0] = f2bf(v.x); o[1] = f2bf(v.y); o[2] = f2bf(v.z); o[3] = f2bf(v.w);
  *(u16x4*)(xb + i) = o;
}

// ---------------- kernel 0b: W[k][n] f32 -> Wt[n][k] bf16 (1024x1024) ----------------
__global__ __launch_bounds__(256) void k_transpose(
    const float* __restrict__ W0, const float* __restrict__ W1,
    const float* __restrict__ W2, const float* __restrict__ W3,
    unsigned short* __restrict__ T0, unsigned short* __restrict__ T1,
    unsigned short* __restrict__ T2, unsigned short* __restrict__ T3) {
  const int z = blockIdx.z;
  const float* W = (z == 0) ? W0 : (z == 1) ? W1 : (z == 2) ? W2 : W3;
  unsigned short* T = (z == 0) ? T0 : (z == 1) ? T1 : (z == 2) ? T2 : T3;
  __shared__ unsigned short buf[32][33];
  const int k0 = blockIdx.x * 32, n0 = blockIdx.y * 32;
  const int tx = threadIdx.x, ty = threadIdx.y;   // (32, 8)
#pragma unroll
  for (int j = 0; j < 4; ++j) {
    int r = ty + j * 8;
    buf[r][tx] = f2bf(W[(size_t)(k0 + r) * 1024 + n0 + tx]);
  }
  __syncthreads();
#pragma unroll
  for (int j = 0; j < 4; ++j) {
    int c = ty + j * 8;
    T[(size_t)(n0 + c) * 1024 + k0 + tx] = buf[tx][c];
  }
}

// ---------------- shared GEMM main loop (gload_lds + dbuf) ----------------
// C(128x128) = A(128xK) * Wt(128xK)^T, K=1024, bf16 MFMA 16x16x32, BK=32.
// LDS tile [128][32] linear; source pre-swizzled chunk ^= row&3.
DI void stage_gemm(const unsigned short* __restrict__ src, unsigned short* dst,
                   int row0, int k0, int tid, int wid) {
#pragma unroll
  for (int i = 0; i < 2; ++i) {
    int T = i * 256 + tid;
    int row = T >> 2, ch = T & 3;
    int sch = ch ^ (row & 3);
    gload16(&src[(size_t)(row0 + row) * 1024 + k0 + sch * 8],
            &dst[(i * 256 + wid * 64) * 8]);
  }
}

DI void gemm_main(const unsigned short* __restrict__ A,
                  const unsigned short* __restrict__ Bm,
                  unsigned short* As, unsigned short* Bs,
                  int m0, int n0, f32x4 acc[4][4]) {
  const int tid = threadIdx.x;
  const int lane = tid & 63, wid = tid >> 6;
  const int wr = wid >> 1, wc = wid & 1;
  const int g = lane >> 4, lq = lane & 15;

  stage_gemm(A, As, m0, 0, tid, wid);
  stage_gemm(Bm, Bs, n0, 0, tid, wid);
  __syncthreads();
  int buf = 0;
  for (int k0 = 0; k0 < 1024; k0 += 32) {
    if (k0 + 32 < 1024) {
      stage_gemm(A, As + (buf ^ 1) * 4096, m0, k0 + 32, tid, wid);
      stage_gemm(Bm, Bs + (buf ^ 1) * 4096, n0, k0 + 32, tid, wid);
    }
    const unsigned short* Ab = As + buf * 4096;
    const unsigned short* Bb = Bs + buf * 4096;
    U8 af[4], bfr[4];
#pragma unroll
    for (int f = 0; f < 4; ++f) {
      af[f].u  = *(const u16x8*)&Ab[(wr * 64 + f * 16 + lq) * 32 + ((g ^ (lq & 3)) * 8)];
      bfr[f].u = *(const u16x8*)&Bb[(wc * 64 + f * 16 + lq) * 32 + ((g ^ (lq & 3)) * 8)];
    }
#pragma unroll
    for (int i = 0; i < 4; ++i)
#pragma unroll
      for (int j = 0; j < 4; ++j)
        acc[i][j] = __builtin_amdgcn_mfma_f32_16x16x32_bf16(af[i].b, bfr[j].b,
                                                            acc[i][j], 0, 0, 0);
    __syncthreads();
    buf ^= 1;
  }
}

// ---------------- kernel 1: QKV projection ----------------
__global__ __launch_bounds__(256) void k_gemm_qkv(
    const unsigned short* __restrict__ xb,
    const unsigned short* __restrict__ Wqt, const unsigned short* __restrict__ Wkt,
    const unsigned short* __restrict__ Wvt,
    const float* __restrict__ bq, const float* __restrict__ bk,
    const float* __restrict__ bv,
    unsigned short* __restrict__ Qo, unsigned short* __restrict__ Ko,
    unsigned short* __restrict__ Vto) {
  __shared__ unsigned short As[2 * 4096];
  __shared__ unsigned short Bs[2 * 4096];
  const int z = blockIdx.z;
  const unsigned short* Bm = (z == 0) ? Wqt : (z == 1) ? Wkt : Wvt;
  const float* bias = (z == 0) ? bq : (z == 1) ? bk : bv;

  f32x4 acc[4][4];
#pragma unroll
  for (int i = 0; i < 4; ++i)
#pragma unroll
    for (int j = 0; j < 4; ++j) acc[i][j] = f32x4{0.f, 0.f, 0.f, 0.f};

  const int m0 = blockIdx.x * 128, n0 = blockIdx.y * 128;
  gemm_main(xb, Bm, As, Bs, m0, n0, acc);

  const int lane = threadIdx.x & 63, wid = threadIdx.x >> 6;
  const int wr = wid >> 1, wc = wid & 1;
  const int g = lane >> 4, lq = lane & 15;
  unsigned short* dstQK = (z == 0) ? Qo : Ko;
#pragma unroll
  for (int j = 0; j < 4; ++j) {
    int col = n0 + wc * 64 + j * 16 + lq;
    float bv_ = bias[col];
    int h = col >> 6, d = col & 63;
#pragma unroll
    for (int i = 0; i < 4; ++i) {
#pragma unroll
      for (int r = 0; r < 4; ++r) {
        int row = m0 + wr * 64 + i * 16 + g * 4 + r;
        int b = row >> 11, s = row & 2047;
        unsigned short hv = f2bf(acc[i][j][r] + bv_);
        if (z < 2)
          dstQK[(((size_t)(b * 16 + h)) * 2048 + s) * 64 + d] = hv;
        else
          Vto[(((size_t)(b * 16 + h)) * 64 + d) * 2048 + s] = hv;
      }
    }
  }
}

// ---------------- kernel 3: output projection (fp32 out + bias) ----------------
__global__ __launch_bounds__(256) void k_gemm_out(
    const unsigned short* __restrict__ Ob, const unsigned short* __restrict__ Wot,
    const float* __restrict__ bo, float* __restrict__ out) {
  __shared__ unsigned short As[2 * 4096];
  __shared__ unsigned short Bs[2 * 4096];
  f32x4 acc[4][4];
#pragma unroll
  for (int i = 0; i < 4; ++i)
#pragma unroll
    for (int j = 0; j < 4; ++j) acc[i][j] = f32x4{0.f, 0.f, 0.f, 0.f};

  const int m0 = blockIdx.x * 128, n0 = blockIdx.y * 128;
  gemm_main(Ob, Wot, As, Bs, m0, n0, acc);

  const int lane = threadIdx.x & 63, wid = threadIdx.x >> 6;
  const int wr = wid >> 1, wc = wid & 1;
  const int g = lane >> 4, lq = lane & 15;
#pragma unroll
  for (int j = 0; j < 4; ++j) {
    int col = n0 + wc * 64 + j * 16 + lq;
    float bv_ = bo[col];
#pragma unroll
    for (int i = 0; i < 4; ++i)
#pragma unroll
      for (int r = 0; r < 4; ++r) {
        int row = m0 + wr * 64 + i * 16 + g * 4 + r;
        out[(size_t)row * 1024 + col] = acc[i][j][r] + bv_;
      }
  }
}

// ---------------- kernel 2: flash attention v8 ------------------------------
// 512 blocks (2/CU), XCD-chunked (4 bh/XCD), pair (qb, 31-qb) -> uniform 33
// tiles. 4 waves, wave owns 16 q rows. K/V 64-tile LDS dbuf, counted vmcnt(4).
// p = exp2(|s|*0.125*log2e) with FIXED shift 0 (exact: softmax shift-invariant,
// overflow impossible for |s| < 660). l accumulated in 4 lane-local partials,
// reduced once in epilogue. Causal cndmask only on the diagonal tile.
template<bool MASKED>
DI void ptile(f32x4 sacc[4], f32x4& lacc, unsigned int pk[4][2], int qloc, int g) {
  const float SC = 0.18033688011112042f;   // 0.125 * log2(e)
#pragma unroll
  for (int c = 0; c < 4; ++c) {
#pragma unroll
    for (int r = 0; r < 4; ++r) {
      float sv = fabsf(sacc[c][r]) * SC;
      if (MASKED) {
        int k = c * 16 + g * 4 + r;
        sv = (k <= qloc) ? sv : -1e30f;
      }
      float p = exp2f(sv);
      sacc[c][r] = p;
      lacc[r] += p;
    }
    asm("v_cvt_pk_bf16_f32 %0, %1, %2"
        : "=v"(pk[c][0]) : "v"(sacc[c][0]), "v"(sacc[c][1]));
    asm("v_cvt_pk_bf16_f32 %0, %1, %2"
        : "=v"(pk[c][1]) : "v"(sacc[c][2]), "v"(sacc[c][3]));
  }
}

__global__ __launch_bounds__(256) void k_flash(
    const unsigned short* __restrict__ Q, const unsigned short* __restrict__ Km,
    const unsigned short* __restrict__ Vt, unsigned short* __restrict__ O) {
  const int tid = threadIdx.x;
  const int lane = tid & 63, wid = tid >> 6;
  const int g = lane >> 4, lq = lane & 15;
  const int bid = blockIdx.x;               // 512 blocks
  const int xcd = bid & 7, idx = bid >> 3;  // 64 per XCD
  const int bh = xcd * 4 + (idx >> 4);      // 4 bh per XCD
  const int pairidx = idx & 15;
  const int b = bh >> 4, h = bh & 15;
  const size_t qkbase = (size_t)bh * 2048 * 64;
  const size_t vbase = (size_t)bh * 64 * 2048;
  const int qloc = wid * 16 + lq;

  __shared__ unsigned short Ks[2][64 * 64];
  __shared__ unsigned short Vs[2][64 * 64];

  // stage(buf, t): K tile rows=k, V tile rows=dv; 4 gload16/thread total
  auto stage = [&](int bf, int t) {
    const int kk0 = t * 64;
#pragma unroll
    for (int i = 0; i < 2; ++i) {
      int T = i * 256 + tid;
      int row = T >> 3, ch = T & 7;
      int sch = ch ^ (row & 7);
      gload16(&Km[qkbase + (size_t)(kk0 + row) * 64 + sch * 8],
              &Ks[bf][(i * 2048 + wid * 512)]);
      gload16(&Vt[vbase + (size_t)row * 2048 + kk0 + sch * 8],
              &Vs[bf][(i * 2048 + wid * 512)]);
    }
  };

  for (int ph = 0; ph < 2; ++ph) {
    const int qb = ph ? (31 - pairidx) : pairidx;
    const int q0 = qb * 64;
    const int qrow = q0 + qloc;

    U8 aq0, aq1;
    {
      const unsigned short* qp = &Q[qkbase + (size_t)qrow * 64 + g * 8];
      aq0.u = *(const u16x8*)qp;
      aq1.u = *(const u16x8*)(qp + 32);
    }
    f32x4 lacc = f32x4{0.f, 0.f, 0.f, 0.f};
    f32x4 oacc[4];
#pragma unroll
    for (int c = 0; c < 4; ++c) oacc[c] = f32x4{0.f, 0.f, 0.f, 0.f};

    const int nt = qb + 1;
    stage(0, 0);
    if (nt > 1) stage(1, 1);
    int buf = 0;
    for (int t = 0; t < nt; ++t) {
      if (t + 1 < nt) WAIT_VM4; else WAIT_VM0;
      BARRIER;
      // ---- QK^T: A = K frags from LDS, B = Q frag
      f32x4 sacc[4];
      __builtin_amdgcn_s_setprio(1);
#pragma unroll
      for (int c = 0; c < 4; ++c) {
        U8 kf0, kf1;
        kf0.u = *(const u16x8*)&Ks[buf][(c * 16 + lq) * 64 + (((0 * 4 + g) ^ (lq & 7)) * 8)];
        kf1.u = *(const u16x8*)&Ks[buf][(c * 16 + lq) * 64 + (((1 * 4 + g) ^ (lq & 7)) * 8)];
        sacc[c] = __builtin_amdgcn_mfma_f32_16x16x32_bf16(kf0.b, aq0.b,
                                                          f32x4{0.f, 0.f, 0.f, 0.f}, 0, 0, 0);
        sacc[c] = __builtin_amdgcn_mfma_f32_16x16x32_bf16(kf1.b, aq1.b, sacc[c], 0, 0, 0);
      }
      __builtin_amdgcn_s_setprio(0);
      // ---- p = exp2(|s|*SC), mask only on diagonal tile; lane-local l partials
      unsigned int pk[4][2];
      if (t == nt - 1) ptile<true>(sacc, lacc, pk, qloc, g);
      else            ptile<false>(sacc, lacc, pk, qloc, g);
      // ---- re-fragment P; PV: A = V^T frags from LDS
      __builtin_amdgcn_s_setprio(1);
#pragma unroll
      for (int hh = 0; hh < 2; ++hh) {
        PB pb;
#pragma unroll
        for (int w2 = 0; w2 < 4; ++w2) {
          int src = (((g & 1) * 2 + (w2 >> 1)) << 4) + lq;
          unsigned int lo = __shfl(pk[hh * 2 + 0][w2 & 1], src, 64);
          unsigned int hi = __shfl(pk[hh * 2 + 1][w2 & 1], src, 64);
          pb.w[w2] = (g >> 1) ? hi : lo;
        }
#pragma unroll
        for (int c = 0; c < 4; ++c) {
          U8 vf;
          vf.u = *(const u16x8*)&Vs[buf][(c * 16 + lq) * 64 + (((hh * 4 + g) ^ (lq & 7)) * 8)];
          oacc[c] = __builtin_amdgcn_mfma_f32_16x16x32_bf16(vf.b, pb.b, oacc[c], 0, 0, 0);
        }
      }
      __builtin_amdgcn_s_setprio(0);
      WAIT_LGKM;
      BARRIER;
      if (t + 2 < nt) stage(buf, t + 2);
      buf ^= 1;
    }
    // ---- epilogue: reduce l across the 4 k-groups, then O = oacc / l
    float lsum = (lacc[0] + lacc[1]) + (lacc[2] + lacc[3]);
    lsum += __shfl_xor(lsum, 16, 64);
    lsum += __shfl_xor(lsum, 32, 64);
    float inv_l = 1.0f / lsum;
#pragma unroll
    for (int c = 0; c < 4; ++c) {
      u16x4 ov;
#pragma unroll
      for (int r = 0; r < 4; ++r) ov[r] = f2bf(oacc[c][r] * inv_l);
      *(u16x4*)&O[((size_t)(b * 2048 + qrow)) * 1024 + h * 64 + c * 16 + g * 4] = ov;
    }
  }
}

// ---------------- launch ----------------
extern "C" void kernel_launch(void* const* d_in, const int* in_sizes, int n_in,
                              void* d_out, int out_size, void* d_ws, size_t ws_size,
                              hipStream_t stream) {
  const float* x  = (const float*)d_in[0];
  const float* Wq = (const float*)d_in[1];
  const float* bq = (const float*)d_in[2];
  const float* Wk = (const float*)d_in[3];
  const float* bk = (const float*)d_in[4];
  const float* Wv = (const float*)d_in[5];
  const float* bv = (const float*)d_in[6];
  const float* Wo = (const float*)d_in[7];
  const float* bo = (const float*)d_in[8];
  float* out = (float*)d_out;

  char* ws = (char*)d_ws;
  const size_t MB = 1024 * 1024;
  unsigned short* xb   = (unsigned short*)(ws + 0 * MB);   // 8 MB
  unsigned short* Wqt  = (unsigned short*)(ws + 8 * MB);   // 2 MB
  unsigned short* Wkt  = (unsigned short*)(ws + 10 * MB);  // 2 MB
  unsigned short* Wvt  = (unsigned short*)(ws + 12 * MB);  // 2 MB
  unsigned short* Wot  = (unsigned short*)(ws + 14 * MB);  // 2 MB
  unsigned short* Qws  = (unsigned short*)(ws + 16 * MB);  // 8 MB
  unsigned short* Kws  = (unsigned short*)(ws + 24 * MB);  // 8 MB
  unsigned short* Vtws = (unsigned short*)(ws + 32 * MB);  // 8 MB
  unsigned short* Ows  = (unsigned short*)(ws + 40 * MB);  // 8 MB

  k_conv_x<<<4096, 256, 0, stream>>>(x, xb);
  k_transpose<<<dim3(32, 32, 4), dim3(32, 8), 0, stream>>>(Wq, Wk, Wv, Wo,
                                                           Wqt, Wkt, Wvt, Wot);
  k_gemm_qkv<<<dim3(32, 8, 3), 256, 0, stream>>>(xb, Wqt, Wkt, Wvt, bq, bk, bv,
                                                 Qws, Kws, Vtws);
  k_flash<<<512, 256, 0, stream>>>(Qws, Kws, Vtws, Ows);
  k_gemm_out<<<dim3(32, 8), 256, 0, stream>>>(Ows, Wot, bo, out);
}